// Round 6
// baseline (276.299 us; speedup 1.0000x reference)
//
#include <hip/hip_runtime.h>

#define Bb 2
#define Tt 2048
#define Mm 2048
#define Hh 16
#define Dd 128

typedef __attribute__((ext_vector_type(8))) short bf16x8;
typedef __attribute__((ext_vector_type(4))) float f32x4;
typedef __attribute__((ext_vector_type(16))) float f32x16;

__device__ __forceinline__ unsigned short f2bf(float f) {
    unsigned int u = __builtin_bit_cast(unsigned int, f);
    u += 0x7FFFu + ((u >> 16) & 1u);   // RNE
    return (unsigned short)(u >> 16);
}

__device__ __forceinline__ unsigned int cvt_pk_bf16(float lo, float hi) {
    unsigned int r;
    asm("v_cvt_pk_bf16_f32 %0, %1, %2" : "=v"(r) : "v"(lo), "v"(hi));
    return r;
}

__device__ __forceinline__ float fexp2(float x) { return __builtin_amdgcn_exp2f(x); }

__device__ __forceinline__ void gld16(const void* g, void* l) {
    __builtin_amdgcn_global_load_lds(
        (const __attribute__((address_space(1))) void*)g,
        (__attribute__((address_space(3))) void*)l, 16, 0, 0);
}

// ---------------------------------------------------------------- prep kernels

__global__ __launch_bounds__(256) void cvt_x_kernel(const float* __restrict__ x,
                                                    unsigned short* __restrict__ xb) {
    long i = ((long)blockIdx.x * 256 + threadIdx.x) * 4;
    float4 v = *(const float4*)(x + i);
    unsigned short r0 = f2bf(v.x), r1 = f2bf(v.y), r2 = f2bf(v.z), r3 = f2bf(v.w);
    unsigned int lo = (unsigned int)r0 | ((unsigned int)r1 << 16);
    unsigned int hi = (unsigned int)r2 | ((unsigned int)r3 << 16);
    uint2 packed; packed.x = lo; packed.y = hi;
    *(uint2*)(xb + i) = packed;
}

// plain transpose (for w_ao): in rows x cols fp32 -> out cols x rows bf16
__global__ __launch_bounds__(256) void transpose_cvt(const float* __restrict__ in,
                                                     unsigned short* __restrict__ out,
                                                     int rows, int cols,
                                                     long in_slab, long out_slab) {
    __shared__ float tile[32][33];
    const float* ip = in + (long)blockIdx.z * in_slab;
    unsigned short* op = out + (long)blockIdx.z * out_slab;
    int r0 = blockIdx.x * 32, c0 = blockIdx.y * 32;
    int tx = threadIdx.x & 31, ty = threadIdx.x >> 5;
#pragma unroll
    for (int j = 0; j < 32; j += 8)
        tile[ty + j][tx] = ip[(long)(r0 + ty + j) * cols + c0 + tx];
    __syncthreads();
#pragma unroll
    for (int j = 0; j < 32; j += 8)
        op[(long)(c0 + ty + j) * rows + r0 + tx] = f2bf(tile[tx][ty + j]);
}

// qkv weights: transpose + within-head column permutation for 32-col fragments:
// ord(d) = (d>>6) + 2*((d>>5)&1);  p = (d&31) + 32*ord.
// Pairs (d, d+64) land in adjacent 32-col fragments at the SAME lane.
__global__ __launch_bounds__(256) void transpose_cvt_qkv(
    const float* __restrict__ wq, const float* __restrict__ wk, const float* __restrict__ wv,
    unsigned short* __restrict__ outBase) {
    __shared__ float tile[32][33];
    const int z = blockIdx.z;             // 0..47
    const int which = z >> 4, slab = z & 15;
    const float* ip = (which == 0 ? wq : which == 1 ? wk : wv) + (long)slab * 2048 * 128;
    unsigned short* op = outBase + (long)which * 4194304 + (long)slab * 128 * 2048;
    int r0 = blockIdx.x * 32, c0 = blockIdx.y * 32;   // r over k(2048), c over d(128)
    int tx = threadIdx.x & 31, ty = threadIdx.x >> 5;
#pragma unroll
    for (int j = 0; j < 32; j += 8)
        tile[ty + j][tx] = ip[(long)(r0 + ty + j) * 128 + c0 + tx];
    __syncthreads();
#pragma unroll
    for (int j = 0; j < 32; j += 8) {
        int d = c0 + ty + j;
        int ord = (d >> 6) + 2 * ((d >> 5) & 1);
        int p = (d & 31) + 32 * ord;
        op[(long)p * 2048 + r0 + tx] = f2bf(tile[tx][ty + j]);
    }
}

__global__ __launch_bounds__(256) void rope_tab(float* __restrict__ cosT,
                                                float* __restrict__ sinT) {
    int idx = blockIdx.x * 256 + threadIdx.x;   // T*64
    int t = idx >> 6, d = idx & 63;
    float freq = powf(10000.f, -(float)d / 64.f);
    float ang = (float)t * freq;
    sinT[idx] = sinf(ang);
    cosT[idx] = cosf(ang);
}

// ---------------------------------------------------------------- QKV projection GEMM
// 128x256 tile, 4 waves (2M x 2N), per-wave 64x128, 32x32x16 MFMA, BK=64,
// single-buffered 48KB LDS (A 16KB @0, B 32KB @16384).
__global__ __launch_bounds__(256, 2) void proj_gemm3(
    const unsigned short* __restrict__ xb,
    const unsigned short* __restrict__ wqT,
    const unsigned short* __restrict__ wkT,
    const unsigned short* __restrict__ wvT,
    unsigned short* __restrict__ qO,
    unsigned short* __restrict__ kO,
    unsigned short* __restrict__ vtO,
    const float* __restrict__ cosT,
    const float* __restrict__ sinT) {
    __shared__ __align__(16) char lds[49152];
    const int bm = blockIdx.x;          // 0..31 over M=4096
    const int bn = blockIdx.y;          // 0..23 over N=6144
    const int off = bn * 256;
    const int mode = off >> 11;
    const unsigned short* wT = (mode == 0) ? wqT : (mode == 1) ? wkT : wvT;
    const unsigned short* Asrc = xb + (long)bm * 128 * Mm;
    const unsigned short* Bsrc = wT + (long)(off & 2047) * Mm;

    const int tid = threadIdx.x, lane = tid & 63, wave = tid >> 6;
    const int il = lane & 31, hl = lane >> 5;
    const int wm = wave >> 1, wn = wave & 1;

    f32x16 acc[2][4];
#pragma unroll
    for (int a = 0; a < 2; ++a)
#pragma unroll
        for (int b2 = 0; b2 < 4; ++b2)
#pragma unroll
            for (int e = 0; e < 16; ++e) acc[a][b2][e] = 0.f;

    for (int kt = 0; kt < 32; ++kt) {
        // stage A (128 rows x 64k) + B (256 cols x 64k), pre-swizzled global src
#pragma unroll
        for (int l = 0; l < 4; ++l) {
            int f = l * 256 + tid;
            int r = f >> 3, c = f & 7;
            gld16(Asrc + (long)r * Mm + kt * 64 + ((c ^ (r & 7)) << 3), lds + f * 16);
        }
#pragma unroll
        for (int l = 0; l < 8; ++l) {
            int f = l * 256 + tid;
            int s = f >> 8, q = f & 255, rr = q >> 3, c = q & 7;
            gld16(Bsrc + (long)(s * 32 + rr) * Mm + kt * 64 + ((c ^ (rr & 7)) << 3),
                  lds + 16384 + f * 16);
        }
        asm volatile("s_waitcnt vmcnt(0)" ::: "memory");
        __builtin_amdgcn_s_barrier();

#pragma unroll
        for (int kk = 0; kk < 4; ++kk) {
            bf16x8 af[2], bf[4];
#pragma unroll
            for (int mf = 0; mf < 2; ++mf) {
                int row = wm * 64 + mf * 32 + il;
                af[mf] = *(const bf16x8*)(lds + row * 128 + (((kk * 2 + hl) ^ (row & 7)) << 4));
            }
#pragma unroll
            for (int nf = 0; nf < 4; ++nf) {
                int st = wn * 4 + nf;
                bf[nf] = *(const bf16x8*)(lds + 16384 + st * 4096 + il * 128 +
                                          (((kk * 2 + hl) ^ (il & 7)) << 4));
            }
            __builtin_amdgcn_s_setprio(1);
#pragma unroll
            for (int mf = 0; mf < 2; ++mf)
#pragma unroll
                for (int nf = 0; nf < 4; ++nf)
                    acc[mf][nf] = __builtin_amdgcn_mfma_f32_32x32x16_bf16(af[mf], bf[nf], acc[mf][nf], 0, 0, 0);
            __builtin_amdgcn_s_setprio(0);
        }
        asm volatile("" ::: "memory");
        __builtin_amdgcn_s_barrier();
    }

    const int b = bm >> 4;
    const int t0 = (bm & 15) * 128;
    const int head = ((off & 2047) >> 7) + wn;   // wave owns one full head (128 cols)

    if (mode < 2) {
        const float qs = (mode == 0) ? 0.011271055f : 1.0f;  // log2(e)/D folded into q
        unsigned short* outp = (mode == 0) ? qO : kO;
        long hb = ((long)(b * Hh + head)) * Tt;
#pragma unroll
        for (int mf = 0; mf < 2; ++mf)
#pragma unroll
            for (int np = 0; np < 2; ++np) {       // ord pairs (0,1) and (2,3)
                int d_lo = il + 32 * np;
#pragma unroll
                for (int reg = 0; reg < 16; ++reg) {
                    int r = (reg & 3) + 8 * (reg >> 2) + 4 * hl;
                    int t = t0 + wm * 64 + mf * 32 + r;
                    float c = cosT[t * 64 + d_lo], s = sinT[t * 64 + d_lo];
                    float ev = acc[mf][np * 2][reg], od = acc[mf][np * 2 + 1][reg];
                    long base = (hb + t) * Dd;
                    outp[base + d_lo]      = f2bf((ev * c - od * s) * qs);
                    outp[base + d_lo + 64] = f2bf((ev * s + od * c) * qs);
                }
            }
    } else {
        // V transposed out: per-wave 8KB patch per mf half (128 dslot x 32 t)
        char* patch = lds + wave * 8192;
        long hdbase = ((long)(b * Hh + head)) * Dd;
#pragma unroll
        for (int mf = 0; mf < 2; ++mf) {
#pragma unroll
            for (int nf = 0; nf < 4; ++nf) {
                int dslot = nf * 32 + il;
                int swz = (dslot & 3) << 4;
#pragma unroll
                for (int qg = 0; qg < 4; ++qg) {   // FIX: full 16 regs (was qg<2)
                    uint2 w;
                    w.x = cvt_pk_bf16(acc[mf][nf][qg * 4 + 0], acc[mf][nf][qg * 4 + 1]);
                    w.y = cvt_pk_bf16(acc[mf][nf][qg * 4 + 2], acc[mf][nf][qg * 4 + 3]);
                    *(uint2*)(patch + dslot * 64 + ((qg * 16 + hl * 8) ^ swz)) = w;
                }
            }
            __builtin_amdgcn_s_waitcnt(0);  // lgkm drain (same-wave write->read)
#pragma unroll
            for (int p = 0; p < 8; ++p) {
                int dslot = p * 16 + (lane >> 2);
                int t8 = lane & 3;
                uint4 v = *(const uint4*)(patch + dslot * 64 + ((t8 * 16) ^ ((dslot & 3) << 4)));
                int ordv = dslot >> 5, il2 = dslot & 31;
                int d = il2 + 32 * (ordv >> 1) + 64 * (ordv & 1);
                int tg = t0 + wm * 64 + mf * 32 + t8 * 8;
                *(uint4*)(vtO + (hdbase + d) * Tt + tg) = v;
            }
            __builtin_amdgcn_s_waitcnt(0);
        }
    }
}

// ---------------------------------------------------------------- flash attention (swapped QK^T, 32x32x16)
__global__ __launch_bounds__(256) void attn_kernel(
    const unsigned short* __restrict__ q,
    const unsigned short* __restrict__ k,
    const unsigned short* __restrict__ vt,
    unsigned short* __restrict__ o) {
    __shared__ __align__(16) unsigned short lds[32768];

    const int lid = (int)blockIdx.x;
    const int p = lid & 255;
    const int bh = p & 31;
    const int q0 = p >> 5;
    const int qb = (lid >> 8) ? (15 - q0) : q0;

    const int tid = threadIdx.x, lane = tid & 63, wave = tid >> 6;
    const int h = lane >> 5, iln = lane & 31;

    const unsigned short* qp = q + (long)bh * Tt * Dd;
    const unsigned short* kp = k + (long)bh * Tt * Dd;
    const unsigned short* vp = vt + (long)bh * Dd * Tt;

    const int i_g = qb * 128 + wave * 32 + iln;
    bf16x8 qf[8];
#pragma unroll
    for (int kk = 0; kk < 8; ++kk)
        qf[kk] = *(const bf16x8*)(qp + (long)i_g * Dd + kk * 16 + h * 8);

    f32x16 accO[4];
#pragma unroll
    for (int nb = 0; nb < 4; ++nb)
#pragma unroll
        for (int e = 0; e < 16; ++e) accO[nb][e] = 0.f;

    float m_r = -1e30f, l_r = 0.f;
    const int ntiles = 2 * qb + 2;

    auto stage = [&](int buf, int tix) {
        const int j0s = tix * 64;
#pragma unroll
        for (int it = 0; it < 4; ++it) {
            int f = it * 256 + tid;
            int rk = f >> 4, ck = f & 15;
            gld16(kp + ((long)(j0s + rk) * Dd + ((ck ^ (rk & 7)) << 3)),
                  (char*)lds + buf * 16384 + f * 16);
            int rv = f >> 3, cv = f & 7;
            gld16(vp + ((long)rv * Tt + j0s + ((cv ^ (rv & 7)) << 3)),
                  (char*)lds + 32768 + buf * 16384 + f * 16);
        }
    };

    stage(0, 0);

    for (int tix = 0; tix < ntiles; ++tix) {
        const int cur = tix & 1;
        const int j0 = tix * 64;
        if (tix + 1 < ntiles) {
            stage(cur ^ 1, tix + 1);
            asm volatile("s_waitcnt vmcnt(8)" ::: "memory");
        } else {
            asm volatile("s_waitcnt vmcnt(0)" ::: "memory");
        }
        __builtin_amdgcn_s_barrier();

        const char* Kb = (const char*)lds + cur * 16384;
        const char* Vb = (const char*)lds + 32768 + cur * 16384;

        f32x16 sacc[2];
#pragma unroll
        for (int mb = 0; mb < 2; ++mb)
#pragma unroll
            for (int e = 0; e < 16; ++e) sacc[mb][e] = 0.f;

        __builtin_amdgcn_s_setprio(1);
#pragma unroll
        for (int mb = 0; mb < 2; ++mb) {
            int row = mb * 32 + iln;
            const char* Kr = Kb + row * 256;
            int sw = row & 7;
#pragma unroll
            for (int kk = 0; kk < 8; ++kk) {
                bf16x8 kf = *(const bf16x8*)(Kr + 16 * ((kk * 2 + h) ^ sw));
                sacc[mb] = __builtin_amdgcn_mfma_f32_32x32x16_bf16(kf, qf[kk], sacc[mb], 0, 0, 0);
            }
        }
        __builtin_amdgcn_s_setprio(0);

        const bool domask = (j0 + 63 > qb * 128);
        if (domask) {
#pragma unroll
            for (int mb = 0; mb < 2; ++mb)
#pragma unroll
                for (int reg = 0; reg < 16; ++reg) {
                    int j = j0 + mb * 32 + (reg & 3) + 8 * (reg >> 2) + 4 * h;
                    if (j > i_g) sacc[mb][reg] = -1e30f;
                }
        }

        float red[16];
#pragma unroll
        for (int r = 0; r < 16; ++r) red[r] = fmaxf(sacc[0][r], sacc[1][r]);
#pragma unroll
        for (int s = 8; s >= 1; s >>= 1)
#pragma unroll
            for (int r = 0; r < s; ++r) red[r] = fmaxf(red[r], red[r + s]);
        float mx = fmaxf(red[0], __shfl_xor(red[0], 32, 64));

        if (__any(mx > m_r + 8.f)) {
            float mn = fmaxf(m_r, mx);
            float corr = fexp2(m_r - mn);
            m_r = mn;
            l_r *= corr;
#pragma unroll
            for (int reg = 0; reg < 16; ++reg) {
                int rrow = (reg & 3) + 8 * (reg >> 2) + 4 * h;
                float c = __shfl(corr, rrow, 64);
#pragma unroll
                for (int nb = 0; nb < 4; ++nb) accO[nb][reg] *= c;
            }
        }

        float pe[2][16];
#pragma unroll
        for (int mb = 0; mb < 2; ++mb)
#pragma unroll
            for (int r = 0; r < 16; ++r) pe[mb][r] = fexp2(sacc[mb][r] - m_r);
        float sr[16];
#pragma unroll
        for (int r = 0; r < 16; ++r) sr[r] = pe[0][r] + pe[1][r];
#pragma unroll
        for (int s = 8; s >= 1; s >>= 1)
#pragma unroll
            for (int r = 0; r < s; ++r) sr[r] += sr[r + s];
        l_r += sr[0] + __shfl_xor(sr[0], 32, 64);

        unsigned int pu[2][8];
#pragma unroll
        for (int mb = 0; mb < 2; ++mb)
#pragma unroll
            for (int t = 0; t < 8; ++t)
                pu[mb][t] = cvt_pk_bf16(pe[mb][2 * t], pe[mb][2 * t + 1]);

        unsigned int rv2[2][4];
#pragma unroll
        for (int mb = 0; mb < 2; ++mb)
#pragma unroll
            for (int u = 0; u < 4; ++u) {
                unsigned int sv = h ? pu[mb][(u & 1) + 4 * (u >> 1)]
                                    : pu[mb][2 + (u & 1) + 4 * (u >> 1)];
                rv2[mb][u] = __shfl_xor(sv, 32, 64);
            }

        __builtin_amdgcn_s_setprio(1);
#pragma unroll
        for (int kk2 = 0; kk2 < 4; ++kk2) {
            const int mb = kk2 >> 1, c2 = kk2 & 1;
            unsigned int w0 = h ? rv2[mb][2 * c2 + 0] : pu[mb][4 * c2 + 0];
            unsigned int w1 = h ? rv2[mb][2 * c2 + 1] : pu[mb][4 * c2 + 1];
            unsigned int w2 = h ? pu[mb][4 * c2 + 2] : rv2[mb][2 * c2 + 0];
            unsigned int w3 = h ? pu[mb][4 * c2 + 3] : rv2[mb][2 * c2 + 1];
            uint4 aw; aw.x = w0; aw.y = w1; aw.z = w2; aw.w = w3;
            bf16x8 af = __builtin_bit_cast(bf16x8, aw);
#pragma unroll
            for (int nb = 0; nb < 4; ++nb) {
                int d = nb * 32 + iln;
                int byte = d * 128 + 16 * ((kk2 * 2 + h) ^ (d & 7));
                bf16x8 vf = *(const bf16x8*)(Vb + byte);
                accO[nb] = __builtin_amdgcn_mfma_f32_32x32x16_bf16(af, vf, accO[nb], 0, 0, 0);
            }
        }
        __builtin_amdgcn_s_setprio(0);

        asm volatile("" ::: "memory");
        __builtin_amdgcn_s_barrier();
    }

    const int b = bh >> 4, hh = bh & 15;
    float invl = 1.f / l_r;
#pragma unroll
    for (int reg = 0; reg < 16; ++reg) {
        int rrow = (reg & 3) + 8 * (reg >> 2) + 4 * h;
        float iv = __shfl(invl, rrow, 64);
        int t = qb * 128 + wave * 32 + rrow;
        long base = ((long)(b * Tt + t) * Hh + hh) * Dd;
#pragma unroll
        for (int nb = 0; nb < 4; ++nb)
            o[base + nb * 32 + iln] = f2bf(accO[nb][reg] * iv);
    }
}

// ---------------------------------------------------------------- output projection GEMM
// 128x128 tile, 4 waves (2M x 2N), per-wave 64x64, 32x32x16 MFMA, BK=64, 32KB LDS
__global__ __launch_bounds__(256, 2) void out_gemm3(
    const unsigned short* __restrict__ oIn,
    const unsigned short* __restrict__ woT,
    float* __restrict__ out) {
    __shared__ __align__(16) char lds[32768];
    const int bm = blockIdx.x, bn = blockIdx.y;
    const int tid = threadIdx.x, lane = tid & 63, wave = tid >> 6;
    const int il = lane & 31, hl = lane >> 5;
    const int wm = wave >> 1, wn = wave & 1;

    const unsigned short* Asrc = oIn + (long)bm * 128 * Mm;
    const unsigned short* Bsrc = woT + (long)bn * 128 * Mm;

    f32x16 acc[2][2];
#pragma unroll
    for (int a = 0; a < 2; ++a)
#pragma unroll
        for (int b2 = 0; b2 < 2; ++b2)
#pragma unroll
            for (int e = 0; e < 16; ++e) acc[a][b2][e] = 0.f;

    for (int kt = 0; kt < 32; ++kt) {
#pragma unroll
        for (int l = 0; l < 4; ++l) {
            int f = l * 256 + tid;
            int r = f >> 3, c = f & 7;
            long koff = kt * 64 + ((c ^ (r & 7)) << 3);
            gld16(Asrc + (long)r * Mm + koff, lds + f * 16);
            gld16(Bsrc + (long)r * Mm + koff, lds + 16384 + f * 16);
        }
        asm volatile("s_waitcnt vmcnt(0)" ::: "memory");
        __builtin_amdgcn_s_barrier();

#pragma unroll
        for (int kk = 0; kk < 4; ++kk) {
            bf16x8 af[2], bf[2];
#pragma unroll
            for (int mf = 0; mf < 2; ++mf) {
                int row = wm * 64 + mf * 32 + il;
                af[mf] = *(const bf16x8*)(lds + row * 128 + (((kk * 2 + hl) ^ (row & 7)) << 4));
            }
#pragma unroll
            for (int nf = 0; nf < 2; ++nf) {
                int col = wn * 64 + nf * 32 + il;
                bf[nf] = *(const bf16x8*)(lds + 16384 + col * 128 +
                                          (((kk * 2 + hl) ^ (col & 7)) << 4));
            }
            __builtin_amdgcn_s_setprio(1);
#pragma unroll
            for (int mf = 0; mf < 2; ++mf)
#pragma unroll
                for (int nf = 0; nf < 2; ++nf)
                    acc[mf][nf] = __builtin_amdgcn_mfma_f32_32x32x16_bf16(af[mf], bf[nf], acc[mf][nf], 0, 0, 0);
            __builtin_amdgcn_s_setprio(0);
        }
        asm volatile("" ::: "memory");
        __builtin_amdgcn_s_barrier();
    }

#pragma unroll
    for (int mf = 0; mf < 2; ++mf)
#pragma unroll
        for (int nf = 0; nf < 2; ++nf)
#pragma unroll
            for (int reg = 0; reg < 16; ++reg) {
                int r = (reg & 3) + 8 * (reg >> 2) + 4 * hl;
                long row = bm * 128 + wm * 64 + mf * 32 + r;
                int col = bn * 128 + wn * 64 + nf * 32 + il;
                out[row * Mm + col] = acc[mf][nf][reg];
            }
}

// ---------------------------------------------------------------- launch

extern "C" void kernel_launch(void* const* d_in, const int* in_sizes, int n_in,
                              void* d_out, int out_size, void* d_ws, size_t ws_size,
                              hipStream_t stream) {
    const float* x    = (const float*)d_in[0];
    const float* w_aq = (const float*)d_in[1];
    const float* w_ak = (const float*)d_in[2];
    const float* w_av = (const float*)d_in[3];
    const float* w_ao = (const float*)d_in[4];
    float* out = (float*)d_out;

    char* ws = (char*)d_ws;
    const long SZ_BTM = 16777216;   // B*T*M * 2B
    const long SZ_W   = 8388608;    // 2048*2048 * 2B
    unsigned short* xb  = (unsigned short*)(ws);
    unsigned short* qB  = (unsigned short*)(ws + SZ_BTM);
    unsigned short* kB  = (unsigned short*)(ws + 2 * SZ_BTM);
    unsigned short* vtB = (unsigned short*)(ws + 3 * SZ_BTM);
    unsigned short* oB  = (unsigned short*)(ws + 4 * SZ_BTM);
    unsigned short* wqT = (unsigned short*)(ws + 5 * SZ_BTM);
    unsigned short* wkT = (unsigned short*)(ws + 5 * SZ_BTM + SZ_W);
    unsigned short* wvT = (unsigned short*)(ws + 5 * SZ_BTM + 2 * SZ_W);
    unsigned short* woT = (unsigned short*)(ws + 5 * SZ_BTM + 3 * SZ_W);
    float* cosT = (float*)(ws + 5 * SZ_BTM + 4 * SZ_W);
    float* sinT = (float*)(ws + 5 * SZ_BTM + 4 * SZ_W + 524288);

    cvt_x_kernel<<<8192, 256, 0, stream>>>(x, xb);
    transpose_cvt_qkv<<<dim3(64, 4, 48), 256, 0, stream>>>(w_aq, w_ak, w_av, wqT);
    transpose_cvt<<<dim3(64, 64, 1), 256, 0, stream>>>(w_ao, woT, 2048, 2048, 0, 0);
    rope_tab<<<512, 256, 0, stream>>>(cosT, sinT);

    proj_gemm3<<<dim3(32, 24), 256, 0, stream>>>(xb, wqT, wkT, wvT, qB, kB, vtB, cosT, sinT);
    attn_kernel<<<dim3(512), 256, 0, stream>>>(qB, kB, vtB, oB);
    out_gemm3<<<dim3(32, 16), 256, 0, stream>>>(oB, woT, out);
}

// Round 7
// 267.904 us; speedup vs baseline: 1.0313x; 1.0313x over previous
//
#include <hip/hip_runtime.h>

#define Bb 2
#define Tt 2048
#define Mm 2048
#define Hh 16
#define Dd 128

typedef __attribute__((ext_vector_type(8))) short bf16x8;
typedef __attribute__((ext_vector_type(4))) float f32x4;
typedef __attribute__((ext_vector_type(16))) float f32x16;

__device__ __forceinline__ unsigned short f2bf(float f) {
    unsigned int u = __builtin_bit_cast(unsigned int, f);
    u += 0x7FFFu + ((u >> 16) & 1u);   // RNE
    return (unsigned short)(u >> 16);
}

__device__ __forceinline__ unsigned int cvt_pk_bf16(float lo, float hi) {
    unsigned int r;
    asm("v_cvt_pk_bf16_f32 %0, %1, %2" : "=v"(r) : "v"(lo), "v"(hi));
    return r;
}

__device__ __forceinline__ float fexp2(float x) { return __builtin_amdgcn_exp2f(x); }

__device__ __forceinline__ void gld16(const void* g, void* l) {
    __builtin_amdgcn_global_load_lds(
        (const __attribute__((address_space(1))) void*)g,
        (__attribute__((address_space(3))) void*)l, 16, 0, 0);
}

// ---------------------------------------------------------------- prep kernels

// x (4096 x 2048 fp32) -> xb2 fragment-tiled bf16:
// chunk s in [0,1024) per (mt,kt): kk=s>>8, rb=(s>>6)&3, l=s&63;
// row = rb*32 + (l&31), k = kk*16 + (l>>5)*8  (8 contiguous k elems)
__global__ __launch_bounds__(256) void cvt_x2(const float* __restrict__ x,
                                              unsigned short* __restrict__ xb2) {
    const int blk = blockIdx.x;              // 1024 = 32 mt x 32 kt
    const int mt = blk >> 5, kt = blk & 31;
#pragma unroll
    for (int it = 0; it < 4; ++it) {
        int s = it * 256 + threadIdx.x;
        int row = ((s >> 6) & 3) * 32 + (s & 31);
        int k = (s >> 8) * 16 + ((s >> 5) & 1) * 8;
        const float* sp = x + ((long)(mt * 128 + row)) * 2048 + kt * 64 + k;
        float4 a = *(const float4*)sp;
        float4 b = *(const float4*)(sp + 4);
        uint4 pk;
        pk.x = (unsigned int)f2bf(a.x) | ((unsigned int)f2bf(a.y) << 16);
        pk.y = (unsigned int)f2bf(a.z) | ((unsigned int)f2bf(a.w) << 16);
        pk.z = (unsigned int)f2bf(b.x) | ((unsigned int)f2bf(b.y) << 16);
        pk.w = (unsigned int)f2bf(b.z) | ((unsigned int)f2bf(b.w) << 16);
        *(uint4*)(xb2 + (((long)(mt * 32 + kt)) * 1024 + s) * 8) = pk;
    }
}

// qkv weights (H,M,D fp32) -> fragment-tiled bf16 with RoPE column permutation.
// Per (which, head, kt): output 1024 chunks u' : kk=u'>>8, nf=(u'>>6)&3, l=u'&63;
// d = (l&31) + 64*(nf&1) + 32*(nf>>1);  k = kk*16 + (l>>5)*8 (+e)
// global chunk u = kk*512 + (wn*4+nf)*64 + l  with wn = head&1, ntile = head>>1
__global__ __launch_bounds__(256) void w_qkv_tile(
    const float* __restrict__ wq, const float* __restrict__ wk, const float* __restrict__ wv,
    unsigned short* __restrict__ outBase) {
    __shared__ float tile[64][132];
    const int kt = blockIdx.x;               // 0..31
    const int zy = blockIdx.y;               // 0..47
    const int which = zy >> 4, head = zy & 15;
    const float* src = (which == 0 ? wq : which == 1 ? wk : wv) + (long)head * 2048 * 128;
    const int tid = threadIdx.x;
#pragma unroll
    for (int it = 0; it < 8; ++it) {
        int f = it * 256 + tid;              // 2048 float4s = 64 rows x 32
        int row = f >> 5, c4 = f & 31;
        float4 v = *(const float4*)(src + (long)(kt * 64 + row) * 128 + c4 * 4);
        tile[row][c4 * 4 + 0] = v.x;
        tile[row][c4 * 4 + 1] = v.y;
        tile[row][c4 * 4 + 2] = v.z;
        tile[row][c4 * 4 + 3] = v.w;
    }
    __syncthreads();
    const int ntile = head >> 1, wn = head & 1;
    unsigned short* outp = outBase + (long)which * 4194304 +
                           ((long)(ntile * 32 + kt)) * 2048 * 8;
#pragma unroll
    for (int it = 0; it < 4; ++it) {
        int up = it * 256 + tid;
        int kk = up >> 8, nf = (up >> 6) & 3, l = up & 63;
        int il = l & 31, hl = l >> 5;
        int d = il + 64 * (nf & 1) + 32 * (nf >> 1);
        int kl = kk * 16 + hl * 8;
        uint4 pk;
        pk.x = (unsigned int)f2bf(tile[kl + 0][d]) | ((unsigned int)f2bf(tile[kl + 1][d]) << 16);
        pk.y = (unsigned int)f2bf(tile[kl + 2][d]) | ((unsigned int)f2bf(tile[kl + 3][d]) << 16);
        pk.z = (unsigned int)f2bf(tile[kl + 4][d]) | ((unsigned int)f2bf(tile[kl + 5][d]) << 16);
        pk.w = (unsigned int)f2bf(tile[kl + 6][d]) | ((unsigned int)f2bf(tile[kl + 7][d]) << 16);
        int u = kk * 512 + (wn * 4 + nf) * 64 + l;
        *(uint4*)(outp + (long)u * 8) = pk;
    }
}

// plain transpose (for w_ao): in rows x cols fp32 -> out cols x rows bf16
__global__ __launch_bounds__(256) void transpose_cvt(const float* __restrict__ in,
                                                     unsigned short* __restrict__ out,
                                                     int rows, int cols,
                                                     long in_slab, long out_slab) {
    __shared__ float tile[32][33];
    const float* ip = in + (long)blockIdx.z * in_slab;
    unsigned short* op = out + (long)blockIdx.z * out_slab;
    int r0 = blockIdx.x * 32, c0 = blockIdx.y * 32;
    int tx = threadIdx.x & 31, ty = threadIdx.x >> 5;
#pragma unroll
    for (int j = 0; j < 32; j += 8)
        tile[ty + j][tx] = ip[(long)(r0 + ty + j) * cols + c0 + tx];
    __syncthreads();
#pragma unroll
    for (int j = 0; j < 32; j += 8)
        op[(long)(c0 + ty + j) * rows + r0 + tx] = f2bf(tile[tx][ty + j]);
}

__global__ __launch_bounds__(256) void rope_tab(float* __restrict__ cosT,
                                                float* __restrict__ sinT) {
    int idx = blockIdx.x * 256 + threadIdx.x;   // T*64
    int t = idx >> 6, d = idx & 63;
    float freq = powf(10000.f, -(float)d / 64.f);
    float ang = (float)t * freq;
    sinT[idx] = sinf(ang);
    cosT[idx] = cosf(ang);
}

// ---------------------------------------------------------------- QKV projection GEMM
// 128x256 tile, 4 waves (2M x 2N), per-wave 64x128, 32x32x16 MFMA, BK=64.
// Fragment-major LDS: every operand read AND staging write is lane-linear
// (base + lane*16) -> zero bank conflicts by construction.
__global__ __launch_bounds__(256, 2) void proj_gemm4(
    const unsigned short* __restrict__ xb2,
    const unsigned short* __restrict__ wT2,
    unsigned short* __restrict__ qO,
    unsigned short* __restrict__ kO,
    unsigned short* __restrict__ vtO,
    const float* __restrict__ cosT,
    const float* __restrict__ sinT) {
    __shared__ __align__(16) char lds[49152];   // A 16KB @0, B 32KB @16384
    const int bm = blockIdx.x;          // 0..31 over M=4096
    const int bn = blockIdx.y;          // 0..23 over N=6144
    const int mode = bn >> 3, ntile = bn & 7;
    const unsigned short* Asrc = xb2 + ((long)bm * 32) * 1024 * 8;
    const unsigned short* Bsrc = wT2 + (long)mode * 4194304 + ((long)ntile * 32) * 2048 * 8;

    const int tid = threadIdx.x, lane = tid & 63, wave = tid >> 6;
    const int il = lane & 31, hl = lane >> 5;
    const int wm = wave >> 1, wn = wave & 1;

    f32x16 acc[2][4];
#pragma unroll
    for (int a = 0; a < 2; ++a)
#pragma unroll
        for (int b2 = 0; b2 < 4; ++b2)
#pragma unroll
            for (int e = 0; e < 16; ++e) acc[a][b2][e] = 0.f;

    for (int kt = 0; kt < 32; ++kt) {
#pragma unroll
        for (int l = 0; l < 4; ++l) {
            int s = l * 256 + tid;
            gld16(Asrc + ((long)kt * 1024 + s) * 8, lds + s * 16);
        }
#pragma unroll
        for (int l = 0; l < 8; ++l) {
            int u = l * 256 + tid;
            gld16(Bsrc + ((long)kt * 2048 + u) * 8, lds + 16384 + u * 16);
        }
        asm volatile("s_waitcnt vmcnt(0)" ::: "memory");
        __builtin_amdgcn_s_barrier();

#pragma unroll
        for (int kk = 0; kk < 4; ++kk) {
            bf16x8 af[2], bf[4];
#pragma unroll
            for (int mf = 0; mf < 2; ++mf)
                af[mf] = *(const bf16x8*)(lds + (kk * 256 + (wm * 2 + mf) * 64 + lane) * 16);
#pragma unroll
            for (int nf = 0; nf < 4; ++nf)
                bf[nf] = *(const bf16x8*)(lds + 16384 + (kk * 512 + (wn * 4 + nf) * 64 + lane) * 16);
            __builtin_amdgcn_s_setprio(1);
#pragma unroll
            for (int mf = 0; mf < 2; ++mf)
#pragma unroll
                for (int nf = 0; nf < 4; ++nf)
                    acc[mf][nf] = __builtin_amdgcn_mfma_f32_32x32x16_bf16(af[mf], bf[nf], acc[mf][nf], 0, 0, 0);
            __builtin_amdgcn_s_setprio(0);
        }
        asm volatile("" ::: "memory");
        __builtin_amdgcn_s_barrier();
    }

    const int b = bm >> 4;
    const int t0 = (bm & 15) * 128;
    const int head = ntile * 2 + wn;    // wave owns one full head (128 cols)

    if (mode < 2) {
        const float qs = (mode == 0) ? 0.011271055f : 1.0f;  // log2(e)/D folded into q
        unsigned short* outp = (mode == 0) ? qO : kO;
        long hb = ((long)(b * Hh + head)) * Tt;
#pragma unroll
        for (int mf = 0; mf < 2; ++mf)
#pragma unroll
            for (int np = 0; np < 2; ++np) {       // nf pairs (0,1)=d[0,32), (2,3)=d[32,64)
                int d_lo = il + 32 * np;
#pragma unroll
                for (int reg = 0; reg < 16; ++reg) {
                    int r = (reg & 3) + 8 * (reg >> 2) + 4 * hl;
                    int t = t0 + wm * 64 + mf * 32 + r;
                    float c = cosT[t * 64 + d_lo], s = sinT[t * 64 + d_lo];
                    float ev = acc[mf][np * 2][reg], od = acc[mf][np * 2 + 1][reg];
                    long base = (hb + t) * Dd;
                    outp[base + d_lo]      = f2bf((ev * c - od * s) * qs);
                    outp[base + d_lo + 64] = f2bf((ev * s + od * c) * qs);
                }
            }
    } else {
        // V transposed out: per-wave 8KB patch per mf half (128 dslot x 32 t)
        char* patch = lds + wave * 8192;
        long hdbase = ((long)(b * Hh + head)) * Dd;
#pragma unroll
        for (int mf = 0; mf < 2; ++mf) {
#pragma unroll
            for (int nf = 0; nf < 4; ++nf) {
                int dslot = nf * 32 + il;
                int swz = (dslot & 3) << 4;
#pragma unroll
                for (int qg = 0; qg < 4; ++qg) {
                    uint2 w;
                    w.x = cvt_pk_bf16(acc[mf][nf][qg * 4 + 0], acc[mf][nf][qg * 4 + 1]);
                    w.y = cvt_pk_bf16(acc[mf][nf][qg * 4 + 2], acc[mf][nf][qg * 4 + 3]);
                    *(uint2*)(patch + dslot * 64 + ((qg * 16 + hl * 8) ^ swz)) = w;
                }
            }
            __builtin_amdgcn_s_waitcnt(0);  // lgkm drain (same-wave write->read)
#pragma unroll
            for (int p = 0; p < 8; ++p) {
                int dslot = p * 16 + (lane >> 2);
                int t8 = lane & 3;
                uint4 v = *(const uint4*)(patch + dslot * 64 + ((t8 * 16) ^ ((dslot & 3) << 4)));
                int ordv = dslot >> 5, il2 = dslot & 31;
                int d = il2 + 32 * (ordv >> 1) + 64 * (ordv & 1);
                int tg = t0 + wm * 64 + mf * 32 + t8 * 8;
                *(uint4*)(vtO + (hdbase + d) * Tt + tg) = v;
            }
            __builtin_amdgcn_s_waitcnt(0);
        }
    }
}

// ---------------------------------------------------------------- flash attention (swapped QK^T, 32x32x16)
__global__ __launch_bounds__(256) void attn_kernel(
    const unsigned short* __restrict__ q,
    const unsigned short* __restrict__ k,
    const unsigned short* __restrict__ vt,
    unsigned short* __restrict__ o) {
    __shared__ __align__(16) unsigned short lds[32768];

    const int lid = (int)blockIdx.x;
    const int p = lid & 255;
    const int bh = p & 31;
    const int q0 = p >> 5;
    const int qb = (lid >> 8) ? (15 - q0) : q0;

    const int tid = threadIdx.x, lane = tid & 63, wave = tid >> 6;
    const int h = lane >> 5, iln = lane & 31;

    const unsigned short* qp = q + (long)bh * Tt * Dd;
    const unsigned short* kp = k + (long)bh * Tt * Dd;
    const unsigned short* vp = vt + (long)bh * Dd * Tt;

    const int i_g = qb * 128 + wave * 32 + iln;
    bf16x8 qf[8];
#pragma unroll
    for (int kk = 0; kk < 8; ++kk)
        qf[kk] = *(const bf16x8*)(qp + (long)i_g * Dd + kk * 16 + h * 8);

    f32x16 accO[4];
#pragma unroll
    for (int nb = 0; nb < 4; ++nb)
#pragma unroll
        for (int e = 0; e < 16; ++e) accO[nb][e] = 0.f;

    float m_r = -1e30f, l_r = 0.f;
    const int ntiles = 2 * qb + 2;

    auto stage = [&](int buf, int tix) {
        const int j0s = tix * 64;
#pragma unroll
        for (int it = 0; it < 4; ++it) {
            int f = it * 256 + tid;
            int rk = f >> 4, ck = f & 15;
            gld16(kp + ((long)(j0s + rk) * Dd + ((ck ^ (rk & 7)) << 3)),
                  (char*)lds + buf * 16384 + f * 16);
            int rv = f >> 3, cv = f & 7;
            gld16(vp + ((long)rv * Tt + j0s + ((cv ^ (rv & 7)) << 3)),
                  (char*)lds + 32768 + buf * 16384 + f * 16);
        }
    };

    stage(0, 0);

    for (int tix = 0; tix < ntiles; ++tix) {
        const int cur = tix & 1;
        const int j0 = tix * 64;
        if (tix + 1 < ntiles) {
            stage(cur ^ 1, tix + 1);
            asm volatile("s_waitcnt vmcnt(8)" ::: "memory");
        } else {
            asm volatile("s_waitcnt vmcnt(0)" ::: "memory");
        }
        __builtin_amdgcn_s_barrier();

        const char* Kb = (const char*)lds + cur * 16384;
        const char* Vb = (const char*)lds + 32768 + cur * 16384;

        f32x16 sacc[2];
#pragma unroll
        for (int mb = 0; mb < 2; ++mb)
#pragma unroll
            for (int e = 0; e < 16; ++e) sacc[mb][e] = 0.f;

        __builtin_amdgcn_s_setprio(1);
#pragma unroll
        for (int mb = 0; mb < 2; ++mb) {
            int row = mb * 32 + iln;
            const char* Kr = Kb + row * 256;
            int sw = row & 7;
#pragma unroll
            for (int kk = 0; kk < 8; ++kk) {
                bf16x8 kf = *(const bf16x8*)(Kr + 16 * ((kk * 2 + h) ^ sw));
                sacc[mb] = __builtin_amdgcn_mfma_f32_32x32x16_bf16(kf, qf[kk], sacc[mb], 0, 0, 0);
            }
        }
        __builtin_amdgcn_s_setprio(0);

        const bool domask = (j0 + 63 > qb * 128);
        if (domask) {
#pragma unroll
            for (int mb = 0; mb < 2; ++mb)
#pragma unroll
                for (int reg = 0; reg < 16; ++reg) {
                    int j = j0 + mb * 32 + (reg & 3) + 8 * (reg >> 2) + 4 * h;
                    if (j > i_g) sacc[mb][reg] = -1e30f;
                }
        }

        float red[16];
#pragma unroll
        for (int r = 0; r < 16; ++r) red[r] = fmaxf(sacc[0][r], sacc[1][r]);
#pragma unroll
        for (int s = 8; s >= 1; s >>= 1)
#pragma unroll
            for (int r = 0; r < s; ++r) red[r] = fmaxf(red[r], red[r + s]);
        float mx = fmaxf(red[0], __shfl_xor(red[0], 32, 64));

        if (__any(mx > m_r + 8.f)) {
            float mn = fmaxf(m_r, mx);
            float corr = fexp2(m_r - mn);
            m_r = mn;
            l_r *= corr;
#pragma unroll
            for (int reg = 0; reg < 16; ++reg) {
                int rrow = (reg & 3) + 8 * (reg >> 2) + 4 * h;
                float c = __shfl(corr, rrow, 64);
#pragma unroll
                for (int nb = 0; nb < 4; ++nb) accO[nb][reg] *= c;
            }
        }

        float pe[2][16];
#pragma unroll
        for (int mb = 0; mb < 2; ++mb)
#pragma unroll
            for (int r = 0; r < 16; ++r) pe[mb][r] = fexp2(sacc[mb][r] - m_r);
        float sr[16];
#pragma unroll
        for (int r = 0; r < 16; ++r) sr[r] = pe[0][r] + pe[1][r];
#pragma unroll
        for (int s = 8; s >= 1; s >>= 1)
#pragma unroll
            for (int r = 0; r < s; ++r) sr[r] += sr[r + s];
        l_r += sr[0] + __shfl_xor(sr[0], 32, 64);

        unsigned int pu[2][8];
#pragma unroll
        for (int mb = 0; mb < 2; ++mb)
#pragma unroll
            for (int t = 0; t < 8; ++t)
                pu[mb][t] = cvt_pk_bf16(pe[mb][2 * t], pe[mb][2 * t + 1]);

        unsigned int rv2[2][4];
#pragma unroll
        for (int mb = 0; mb < 2; ++mb)
#pragma unroll
            for (int u = 0; u < 4; ++u) {
                unsigned int sv = h ? pu[mb][(u & 1) + 4 * (u >> 1)]
                                    : pu[mb][2 + (u & 1) + 4 * (u >> 1)];
                rv2[mb][u] = __shfl_xor(sv, 32, 64);
            }

        __builtin_amdgcn_s_setprio(1);
#pragma unroll
        for (int kk2 = 0; kk2 < 4; ++kk2) {
            const int mb = kk2 >> 1, c2 = kk2 & 1;
            unsigned int w0 = h ? rv2[mb][2 * c2 + 0] : pu[mb][4 * c2 + 0];
            unsigned int w1 = h ? rv2[mb][2 * c2 + 1] : pu[mb][4 * c2 + 1];
            unsigned int w2 = h ? pu[mb][4 * c2 + 2] : rv2[mb][2 * c2 + 0];
            unsigned int w3 = h ? pu[mb][4 * c2 + 3] : rv2[mb][2 * c2 + 1];
            uint4 aw; aw.x = w0; aw.y = w1; aw.z = w2; aw.w = w3;
            bf16x8 af = __builtin_bit_cast(bf16x8, aw);
#pragma unroll
            for (int nb = 0; nb < 4; ++nb) {
                int d = nb * 32 + iln;
                int byte = d * 128 + 16 * ((kk2 * 2 + h) ^ (d & 7));
                bf16x8 vf = *(const bf16x8*)(Vb + byte);
                accO[nb] = __builtin_amdgcn_mfma_f32_32x32x16_bf16(af, vf, accO[nb], 0, 0, 0);
            }
        }
        __builtin_amdgcn_s_setprio(0);

        asm volatile("" ::: "memory");
        __builtin_amdgcn_s_barrier();
    }

    const int b = bh >> 4, hh = bh & 15;
    float invl = 1.f / l_r;
#pragma unroll
    for (int reg = 0; reg < 16; ++reg) {
        int rrow = (reg & 3) + 8 * (reg >> 2) + 4 * h;
        float iv = __shfl(invl, rrow, 64);
        int t = qb * 128 + wave * 32 + rrow;
        long base = ((long)(b * Tt + t) * Hh + hh) * Dd;
#pragma unroll
        for (int nb = 0; nb < 4; ++nb)
            o[base + nb * 32 + iln] = f2bf(accO[nb][reg] * iv);
    }
}

// ---------------------------------------------------------------- output projection GEMM
// (R3-proven 16x16 structure: dbuf 64KB, counted vmcnt, low-conflict reads)
__global__ __launch_bounds__(256) void out_gemm(
    const unsigned short* __restrict__ oIn,
    const unsigned short* __restrict__ woT,
    float* __restrict__ out) {
    __shared__ __align__(16) unsigned short smem[32768];
    const int bm = blockIdx.x, bn = blockIdx.y;
    const int tid = threadIdx.x;
    const int lane = tid & 63;
    const int wave = tid >> 6;
    const int g = lane >> 4;
    const int ln = lane & 15;

    const unsigned short* arow = oIn + (long)bm * 128 * Mm;
    const unsigned short* brow = woT + (long)bn * 128 * Mm;

    f32x4 acc[2][8];
#pragma unroll
    for (int a = 0; a < 2; ++a)
#pragma unroll
        for (int b2 = 0; b2 < 8; ++b2)
#pragma unroll
            for (int e = 0; e < 4; ++e) acc[a][b2][e] = 0.f;

    auto stage = [&](int buf, int kt) {
        const int k0 = kt * 64;
#pragma unroll
        for (int it = 0; it < 4; ++it) {
            int f = it * 256 + tid;
            int r = f >> 3, c = f & 7;
            long off = (long)r * Mm + k0 + ((c ^ (r & 7)) << 3);
            gld16(arow + off, (char*)smem + buf * 32768 + f * 16);
            gld16(brow + off, (char*)smem + buf * 32768 + 16384 + f * 16);
        }
    };

    stage(0, 0);

    for (int kt = 0; kt < Mm / 64; ++kt) {
        const int cur = kt & 1;
        if (kt + 1 < Mm / 64) {
            stage(cur ^ 1, kt + 1);
            asm volatile("s_waitcnt vmcnt(8)" ::: "memory");
        } else {
            asm volatile("s_waitcnt vmcnt(0)" ::: "memory");
        }
        __builtin_amdgcn_s_barrier();

        const char* Ab = (const char*)smem + cur * 32768;
        const char* Bv = Ab + 16384;
#pragma unroll
        for (int kc = 0; kc < 2; ++kc) {
            bf16x8 af[2];
#pragma unroll
            for (int rf = 0; rf < 2; ++rf) {
                int row = wave * 32 + rf * 16 + ln;
                int byte = (row * 128 + kc * 64 + g * 16) ^ ((row & 7) << 4);
                af[rf] = *(const bf16x8*)(Ab + byte);
            }
#pragma unroll
            for (int ni = 0; ni < 8; ++ni) {
                int row = ni * 16 + ln;
                int byte = (row * 128 + kc * 64 + g * 16) ^ ((row & 7) << 4);
                bf16x8 bfv = *(const bf16x8*)(Bv + byte);
#pragma unroll
                for (int rf = 0; rf < 2; ++rf)
                    acc[rf][ni] = __builtin_amdgcn_mfma_f32_16x16x32_bf16(af[rf], bfv, acc[rf][ni], 0, 0, 0);
            }
        }
        asm volatile("" ::: "memory");
        __builtin_amdgcn_s_barrier();
    }

#pragma unroll
    for (int rf = 0; rf < 2; ++rf)
#pragma unroll
        for (int reg = 0; reg < 4; ++reg) {
            long row = bm * 128 + wave * 32 + rf * 16 + g * 4 + reg;
#pragma unroll
            for (int ni = 0; ni < 8; ++ni)
                out[row * Mm + bn * 128 + ni * 16 + ln] = acc[rf][ni][reg];
        }
}

// ---------------------------------------------------------------- launch

extern "C" void kernel_launch(void* const* d_in, const int* in_sizes, int n_in,
                              void* d_out, int out_size, void* d_ws, size_t ws_size,
                              hipStream_t stream) {
    const float* x    = (const float*)d_in[0];
    const float* w_aq = (const float*)d_in[1];
    const float* w_ak = (const float*)d_in[2];
    const float* w_av = (const float*)d_in[3];
    const float* w_ao = (const float*)d_in[4];
    float* out = (float*)d_out;

    char* ws = (char*)d_ws;
    const long SZ_BTM = 16777216;   // B*T*M * 2B
    const long SZ_W   = 8388608;    // 2048*2048 * 2B
    unsigned short* xb2 = (unsigned short*)(ws);
    unsigned short* qB  = (unsigned short*)(ws + SZ_BTM);
    unsigned short* kB  = (unsigned short*)(ws + 2 * SZ_BTM);
    unsigned short* vtB = (unsigned short*)(ws + 3 * SZ_BTM);
    unsigned short* oB  = (unsigned short*)(ws + 4 * SZ_BTM);
    unsigned short* wT2 = (unsigned short*)(ws + 5 * SZ_BTM);             // 24MB tiled qkv
    unsigned short* woT = (unsigned short*)(ws + 5 * SZ_BTM + 3 * SZ_W);
    float* cosT = (float*)(ws + 5 * SZ_BTM + 4 * SZ_W);
    float* sinT = (float*)(ws + 5 * SZ_BTM + 4 * SZ_W + 524288);

    cvt_x2<<<1024, 256, 0, stream>>>(x, xb2);
    w_qkv_tile<<<dim3(32, 48), 256, 0, stream>>>(w_aq, w_ak, w_av, wT2);
    transpose_cvt<<<dim3(64, 64, 1), 256, 0, stream>>>(w_ao, woT, 2048, 2048, 0, 0);
    rope_tab<<<512, 256, 0, stream>>>(cosT, sinT);

    proj_gemm4<<<dim3(32, 24), 256, 0, stream>>>(xb2, wT2, qB, kB, vtB, cosT, sinT);
    attn_kernel<<<dim3(512), 256, 0, stream>>>(qB, kB, vtB, oB);
    out_gemm<<<dim3(32, 16), 256, 0, stream>>>(oB, woT, out);
}

// Round 8
// 265.932 us; speedup vs baseline: 1.0390x; 1.0074x over previous
//
#include <hip/hip_runtime.h>

#define Bb 2
#define Tt 2048
#define Mm 2048
#define Hh 16
#define Dd 128

typedef __attribute__((ext_vector_type(8))) short bf16x8;
typedef __attribute__((ext_vector_type(4))) float f32x4;
typedef __attribute__((ext_vector_type(16))) float f32x16;

__device__ __forceinline__ unsigned short f2bf(float f) {
    unsigned int u = __builtin_bit_cast(unsigned int, f);
    u += 0x7FFFu + ((u >> 16) & 1u);   // RNE
    return (unsigned short)(u >> 16);
}

__device__ __forceinline__ unsigned int cvt_pk_bf16(float lo, float hi) {
    unsigned int r;
    asm("v_cvt_pk_bf16_f32 %0, %1, %2" : "=v"(r) : "v"(lo), "v"(hi));
    return r;
}

__device__ __forceinline__ float fexp2(float x) { return __builtin_amdgcn_exp2f(x); }

__device__ __forceinline__ void gld16(const void* g, void* l) {
    __builtin_amdgcn_global_load_lds(
        (const __attribute__((address_space(1))) void*)g,
        (__attribute__((address_space(3))) void*)l, 16, 0, 0);
}

// ---------------------------------------------------------------- prep kernels

// x (4096 x 2048 fp32) -> xb2 fragment-tiled bf16:
// chunk s in [0,1024) per (mt,kt): kk=s>>8, rb=(s>>6)&3, l=s&63;
// row = rb*32 + (l&31), k = kk*16 + (l>>5)*8  (8 contiguous k elems)
__global__ __launch_bounds__(256) void cvt_x2(const float* __restrict__ x,
                                              unsigned short* __restrict__ xb2) {
    const int blk = blockIdx.x;              // 1024 = 32 mt x 32 kt
    const int mt = blk >> 5, kt = blk & 31;
#pragma unroll
    for (int it = 0; it < 4; ++it) {
        int s = it * 256 + threadIdx.x;
        int row = ((s >> 6) & 3) * 32 + (s & 31);
        int k = (s >> 8) * 16 + ((s >> 5) & 1) * 8;
        const float* sp = x + ((long)(mt * 128 + row)) * 2048 + kt * 64 + k;
        float4 a = *(const float4*)sp;
        float4 b = *(const float4*)(sp + 4);
        uint4 pk;
        pk.x = (unsigned int)f2bf(a.x) | ((unsigned int)f2bf(a.y) << 16);
        pk.y = (unsigned int)f2bf(a.z) | ((unsigned int)f2bf(a.w) << 16);
        pk.z = (unsigned int)f2bf(b.x) | ((unsigned int)f2bf(b.y) << 16);
        pk.w = (unsigned int)f2bf(b.z) | ((unsigned int)f2bf(b.w) << 16);
        *(uint4*)(xb2 + (((long)(mt * 32 + kt)) * 1024 + s) * 8) = pk;
    }
}

// qkv weights (H,M,D fp32) -> fragment-tiled bf16 with RoPE column permutation.
__global__ __launch_bounds__(256) void w_qkv_tile(
    const float* __restrict__ wq, const float* __restrict__ wk, const float* __restrict__ wv,
    unsigned short* __restrict__ outBase) {
    __shared__ float tile[64][132];
    const int kt = blockIdx.x;               // 0..31
    const int zy = blockIdx.y;               // 0..47
    const int which = zy >> 4, head = zy & 15;
    const float* src = (which == 0 ? wq : which == 1 ? wk : wv) + (long)head * 2048 * 128;
    const int tid = threadIdx.x;
#pragma unroll
    for (int it = 0; it < 8; ++it) {
        int f = it * 256 + tid;              // 2048 float4s = 64 rows x 32
        int row = f >> 5, c4 = f & 31;
        float4 v = *(const float4*)(src + (long)(kt * 64 + row) * 128 + c4 * 4);
        tile[row][c4 * 4 + 0] = v.x;
        tile[row][c4 * 4 + 1] = v.y;
        tile[row][c4 * 4 + 2] = v.z;
        tile[row][c4 * 4 + 3] = v.w;
    }
    __syncthreads();
    const int ntile = head >> 1, wn = head & 1;
    unsigned short* outp = outBase + (long)which * 4194304 +
                           ((long)(ntile * 32 + kt)) * 2048 * 8;
#pragma unroll
    for (int it = 0; it < 4; ++it) {
        int up = it * 256 + tid;
        int kk = up >> 8, nf = (up >> 6) & 3, l = up & 63;
        int il = l & 31, hl = l >> 5;
        int d = il + 64 * (nf & 1) + 32 * (nf >> 1);
        int kl = kk * 16 + hl * 8;
        uint4 pk;
        pk.x = (unsigned int)f2bf(tile[kl + 0][d]) | ((unsigned int)f2bf(tile[kl + 1][d]) << 16);
        pk.y = (unsigned int)f2bf(tile[kl + 2][d]) | ((unsigned int)f2bf(tile[kl + 3][d]) << 16);
        pk.z = (unsigned int)f2bf(tile[kl + 4][d]) | ((unsigned int)f2bf(tile[kl + 5][d]) << 16);
        pk.w = (unsigned int)f2bf(tile[kl + 6][d]) | ((unsigned int)f2bf(tile[kl + 7][d]) << 16);
        int u = kk * 512 + (wn * 4 + nf) * 64 + l;
        *(uint4*)(outp + (long)u * 8) = pk;
    }
}

// plain transpose (for w_ao): in rows x cols fp32 -> out cols x rows bf16
__global__ __launch_bounds__(256) void transpose_cvt(const float* __restrict__ in,
                                                     unsigned short* __restrict__ out,
                                                     int rows, int cols,
                                                     long in_slab, long out_slab) {
    __shared__ float tile[32][33];
    const float* ip = in + (long)blockIdx.z * in_slab;
    unsigned short* op = out + (long)blockIdx.z * out_slab;
    int r0 = blockIdx.x * 32, c0 = blockIdx.y * 32;
    int tx = threadIdx.x & 31, ty = threadIdx.x >> 5;
#pragma unroll
    for (int j = 0; j < 32; j += 8)
        tile[ty + j][tx] = ip[(long)(r0 + ty + j) * cols + c0 + tx];
    __syncthreads();
#pragma unroll
    for (int j = 0; j < 32; j += 8)
        op[(long)(c0 + ty + j) * rows + r0 + tx] = f2bf(tile[tx][ty + j]);
}

__global__ __launch_bounds__(256) void rope_tab(float* __restrict__ cosT,
                                                float* __restrict__ sinT) {
    int idx = blockIdx.x * 256 + threadIdx.x;   // T*64
    int t = idx >> 6, d = idx & 63;
    float freq = powf(10000.f, -(float)d / 64.f);
    float ang = (float)t * freq;
    sinT[idx] = sinf(ang);
    cosT[idx] = cosf(ang);
}

// ---------------------------------------------------------------- QKV projection GEMM
// 128x256 tile, 4 waves (2M x 2N), per-wave 64x128, 32x32x16 MFMA, BK=32,
// fragment-major LDS (zero-conflict lane-linear reads/writes),
// DOUBLE-BUFFERED with counted vmcnt(6) — loads stay in flight across barriers.
// 2x24KB buffers = 48KB -> 3 blocks/CU.
__global__ __launch_bounds__(256, 3) void proj_gemm5(
    const unsigned short* __restrict__ xb2,
    const unsigned short* __restrict__ wT2,
    unsigned short* __restrict__ qO,
    unsigned short* __restrict__ kO,
    unsigned short* __restrict__ vtO,
    const float* __restrict__ cosT,
    const float* __restrict__ sinT) {
    __shared__ __align__(16) char lds[49152];   // buf b @ b*24576: A 8KB, B 16KB @+8192
    const int bm = blockIdx.x;          // 0..31 over M=4096
    const int bn = blockIdx.y;          // 0..23 over N=6144
    const int mode = bn >> 3, ntile = bn & 7;
    const unsigned short* Asrc = xb2 + ((long)bm * 32) * 1024 * 8;
    const unsigned short* Bsrc = wT2 + (long)mode * 4194304 + ((long)ntile * 32) * 2048 * 8;

    const int tid = threadIdx.x, lane = tid & 63, wave = tid >> 6;
    const int il = lane & 31, hl = lane >> 5;
    const int wm = wave >> 1, wn = wave & 1;

    f32x16 acc[2][4];
#pragma unroll
    for (int a = 0; a < 2; ++a)
#pragma unroll
        for (int b2 = 0; b2 < 4; ++b2)
#pragma unroll
            for (int e = 0; e < 16; ++e) acc[a][b2][e] = 0.f;

    // stage half-K-tile kt2 (32 k) into buffer buf: A 512 chunks, B 1024 chunks
    auto stage = [&](int buf, int kt2) {
        const int kt = kt2 >> 1, hf = kt2 & 1;
        const unsigned short* A0 = Asrc + ((long)kt * 1024 + hf * 512) * 8;
        const unsigned short* B0 = Bsrc + ((long)kt * 2048 + hf * 1024) * 8;
        char* dst = lds + buf * 24576;
#pragma unroll
        for (int l = 0; l < 2; ++l) {
            int s = l * 256 + tid;
            gld16(A0 + (long)s * 8, dst + s * 16);
        }
#pragma unroll
        for (int l = 0; l < 4; ++l) {
            int u = l * 256 + tid;
            gld16(B0 + (long)u * 8, dst + 8192 + u * 16);
        }
    };

    stage(0, 0);

    for (int kt2 = 0; kt2 < 64; ++kt2) {
        const int cur = kt2 & 1;
        if (kt2 + 1 < 64) {
            stage(cur ^ 1, kt2 + 1);
            asm volatile("s_waitcnt vmcnt(6)" ::: "memory");   // current buffer's 6 done
        } else {
            asm volatile("s_waitcnt vmcnt(0)" ::: "memory");
        }
        __builtin_amdgcn_s_barrier();

        const char* bc = lds + cur * 24576;
#pragma unroll
        for (int kk2 = 0; kk2 < 2; ++kk2) {
            bf16x8 af[2], bf[4];
#pragma unroll
            for (int mf = 0; mf < 2; ++mf)
                af[mf] = *(const bf16x8*)(bc + (kk2 * 256 + (wm * 2 + mf) * 64 + lane) * 16);
#pragma unroll
            for (int nf = 0; nf < 4; ++nf)
                bf[nf] = *(const bf16x8*)(bc + 8192 + (kk2 * 512 + (wn * 4 + nf) * 64 + lane) * 16);
            __builtin_amdgcn_s_setprio(1);
#pragma unroll
            for (int mf = 0; mf < 2; ++mf)
#pragma unroll
                for (int nf = 0; nf < 4; ++nf)
                    acc[mf][nf] = __builtin_amdgcn_mfma_f32_32x32x16_bf16(af[mf], bf[nf], acc[mf][nf], 0, 0, 0);
            __builtin_amdgcn_s_setprio(0);
        }
        asm volatile("" ::: "memory");
        __builtin_amdgcn_s_barrier();
    }

    const int b = bm >> 4;
    const int t0 = (bm & 15) * 128;
    const int head = ntile * 2 + wn;    // wave owns one full head (128 cols)

    if (mode < 2) {
        const float qs = (mode == 0) ? 0.011271055f : 1.0f;  // log2(e)/D folded into q
        unsigned short* outp = (mode == 0) ? qO : kO;
        long hb = ((long)(b * Hh + head)) * Tt;
#pragma unroll
        for (int mf = 0; mf < 2; ++mf)
#pragma unroll
            for (int np = 0; np < 2; ++np) {       // nf pairs (0,1)=d[0,32), (2,3)=d[32,64)
                int d_lo = il + 32 * np;
#pragma unroll
                for (int reg = 0; reg < 16; ++reg) {
                    int r = (reg & 3) + 8 * (reg >> 2) + 4 * hl;
                    int t = t0 + wm * 64 + mf * 32 + r;
                    float c = cosT[t * 64 + d_lo], s = sinT[t * 64 + d_lo];
                    float ev = acc[mf][np * 2][reg], od = acc[mf][np * 2 + 1][reg];
                    long base = (hb + t) * Dd;
                    outp[base + d_lo]      = f2bf((ev * c - od * s) * qs);
                    outp[base + d_lo + 64] = f2bf((ev * s + od * c) * qs);
                }
            }
    } else {
        // V transposed out: per-wave 8KB patch per mf half (128 dslot x 32 t)
        char* patch = lds + wave * 8192;
        long hdbase = ((long)(b * Hh + head)) * Dd;
#pragma unroll
        for (int mf = 0; mf < 2; ++mf) {
#pragma unroll
            for (int nf = 0; nf < 4; ++nf) {
                int dslot = nf * 32 + il;
                int swz = (dslot & 3) << 4;
#pragma unroll
                for (int qg = 0; qg < 4; ++qg) {
                    uint2 w;
                    w.x = cvt_pk_bf16(acc[mf][nf][qg * 4 + 0], acc[mf][nf][qg * 4 + 1]);
                    w.y = cvt_pk_bf16(acc[mf][nf][qg * 4 + 2], acc[mf][nf][qg * 4 + 3]);
                    *(uint2*)(patch + dslot * 64 + ((qg * 16 + hl * 8) ^ swz)) = w;
                }
            }
            __builtin_amdgcn_s_waitcnt(0);  // lgkm drain (same-wave write->read)
#pragma unroll
            for (int p = 0; p < 8; ++p) {
                int dslot = p * 16 + (lane >> 2);
                int t8 = lane & 3;
                uint4 v = *(const uint4*)(patch + dslot * 64 + ((t8 * 16) ^ ((dslot & 3) << 4)));
                int ordv = dslot >> 5, il2 = dslot & 31;
                int d = il2 + 32 * (ordv >> 1) + 64 * (ordv & 1);
                int tg = t0 + wm * 64 + mf * 32 + t8 * 8;
                *(uint4*)(vtO + (hdbase + d) * Tt + tg) = v;
            }
            __builtin_amdgcn_s_waitcnt(0);
        }
    }
}

// ---------------------------------------------------------------- flash attention (swapped QK^T, 32x32x16)
__global__ __launch_bounds__(256) void attn_kernel(
    const unsigned short* __restrict__ q,
    const unsigned short* __restrict__ k,
    const unsigned short* __restrict__ vt,
    unsigned short* __restrict__ o) {
    __shared__ __align__(16) unsigned short lds[32768];

    const int lid = (int)blockIdx.x;
    const int p = lid & 255;
    const int bh = p & 31;
    const int q0 = p >> 5;
    const int qb = (lid >> 8) ? (15 - q0) : q0;

    const int tid = threadIdx.x, lane = tid & 63, wave = tid >> 6;
    const int h = lane >> 5, iln = lane & 31;

    const unsigned short* qp = q + (long)bh * Tt * Dd;
    const unsigned short* kp = k + (long)bh * Tt * Dd;
    const unsigned short* vp = vt + (long)bh * Dd * Tt;

    const int i_g = qb * 128 + wave * 32 + iln;
    bf16x8 qf[8];
#pragma unroll
    for (int kk = 0; kk < 8; ++kk)
        qf[kk] = *(const bf16x8*)(qp + (long)i_g * Dd + kk * 16 + h * 8);

    f32x16 accO[4];
#pragma unroll
    for (int nb = 0; nb < 4; ++nb)
#pragma unroll
        for (int e = 0; e < 16; ++e) accO[nb][e] = 0.f;

    float m_r = -1e30f, l_r = 0.f;
    const int ntiles = 2 * qb + 2;

    auto stage = [&](int buf, int tix) {
        const int j0s = tix * 64;
#pragma unroll
        for (int it = 0; it < 4; ++it) {
            int f = it * 256 + tid;
            int rk = f >> 4, ck = f & 15;
            gld16(kp + ((long)(j0s + rk) * Dd + ((ck ^ (rk & 7)) << 3)),
                  (char*)lds + buf * 16384 + f * 16);
            int rv = f >> 3, cv = f & 7;
            gld16(vp + ((long)rv * Tt + j0s + ((cv ^ (rv & 7)) << 3)),
                  (char*)lds + 32768 + buf * 16384 + f * 16);
        }
    };

    stage(0, 0);

    for (int tix = 0; tix < ntiles; ++tix) {
        const int cur = tix & 1;
        const int j0 = tix * 64;
        if (tix + 1 < ntiles) {
            stage(cur ^ 1, tix + 1);
            asm volatile("s_waitcnt vmcnt(8)" ::: "memory");
        } else {
            asm volatile("s_waitcnt vmcnt(0)" ::: "memory");
        }
        __builtin_amdgcn_s_barrier();

        const char* Kb = (const char*)lds + cur * 16384;
        const char* Vb = (const char*)lds + 32768 + cur * 16384;

        f32x16 sacc[2];
#pragma unroll
        for (int mb = 0; mb < 2; ++mb)
#pragma unroll
            for (int e = 0; e < 16; ++e) sacc[mb][e] = 0.f;

        __builtin_amdgcn_s_setprio(1);
#pragma unroll
        for (int mb = 0; mb < 2; ++mb) {
            int row = mb * 32 + iln;
            const char* Kr = Kb + row * 256;
            int sw = row & 7;
#pragma unroll
            for (int kk = 0; kk < 8; ++kk) {
                bf16x8 kf = *(const bf16x8*)(Kr + 16 * ((kk * 2 + h) ^ sw));
                sacc[mb] = __builtin_amdgcn_mfma_f32_32x32x16_bf16(kf, qf[kk], sacc[mb], 0, 0, 0);
            }
        }
        __builtin_amdgcn_s_setprio(0);

        const bool domask = (j0 + 63 > qb * 128);
        if (domask) {
#pragma unroll
            for (int mb = 0; mb < 2; ++mb)
#pragma unroll
                for (int reg = 0; reg < 16; ++reg) {
                    int j = j0 + mb * 32 + (reg & 3) + 8 * (reg >> 2) + 4 * h;
                    if (j > i_g) sacc[mb][reg] = -1e30f;
                }
        }

        float red[16];
#pragma unroll
        for (int r = 0; r < 16; ++r) red[r] = fmaxf(sacc[0][r], sacc[1][r]);
#pragma unroll
        for (int s = 8; s >= 1; s >>= 1)
#pragma unroll
            for (int r = 0; r < s; ++r) red[r] = fmaxf(red[r], red[r + s]);
        float mx = fmaxf(red[0], __shfl_xor(red[0], 32, 64));

        if (__any(mx > m_r + 8.f)) {
            float mn = fmaxf(m_r, mx);
            float corr = fexp2(m_r - mn);
            m_r = mn;
            l_r *= corr;
#pragma unroll
            for (int reg = 0; reg < 16; ++reg) {
                int rrow = (reg & 3) + 8 * (reg >> 2) + 4 * h;
                float c = __shfl(corr, rrow, 64);
#pragma unroll
                for (int nb = 0; nb < 4; ++nb) accO[nb][reg] *= c;
            }
        }

        float pe[2][16];
#pragma unroll
        for (int mb = 0; mb < 2; ++mb)
#pragma unroll
            for (int r = 0; r < 16; ++r) pe[mb][r] = fexp2(sacc[mb][r] - m_r);
        float sr[16];
#pragma unroll
        for (int r = 0; r < 16; ++r) sr[r] = pe[0][r] + pe[1][r];
#pragma unroll
        for (int s = 8; s >= 1; s >>= 1)
#pragma unroll
            for (int r = 0; r < s; ++r) sr[r] += sr[r + s];
        l_r += sr[0] + __shfl_xor(sr[0], 32, 64);

        unsigned int pu[2][8];
#pragma unroll
        for (int mb = 0; mb < 2; ++mb)
#pragma unroll
            for (int t = 0; t < 8; ++t)
                pu[mb][t] = cvt_pk_bf16(pe[mb][2 * t], pe[mb][2 * t + 1]);

        unsigned int rv2[2][4];
#pragma unroll
        for (int mb = 0; mb < 2; ++mb)
#pragma unroll
            for (int u = 0; u < 4; ++u) {
                unsigned int sv = h ? pu[mb][(u & 1) + 4 * (u >> 1)]
                                    : pu[mb][2 + (u & 1) + 4 * (u >> 1)];
                rv2[mb][u] = __shfl_xor(sv, 32, 64);
            }

        __builtin_amdgcn_s_setprio(1);
#pragma unroll
        for (int kk2 = 0; kk2 < 4; ++kk2) {
            const int mb = kk2 >> 1, c2 = kk2 & 1;
            unsigned int w0 = h ? rv2[mb][2 * c2 + 0] : pu[mb][4 * c2 + 0];
            unsigned int w1 = h ? rv2[mb][2 * c2 + 1] : pu[mb][4 * c2 + 1];
            unsigned int w2 = h ? pu[mb][4 * c2 + 2] : rv2[mb][2 * c2 + 0];
            unsigned int w3 = h ? pu[mb][4 * c2 + 3] : rv2[mb][2 * c2 + 1];
            uint4 aw; aw.x = w0; aw.y = w1; aw.z = w2; aw.w = w3;
            bf16x8 af = __builtin_bit_cast(bf16x8, aw);
#pragma unroll
            for (int nb = 0; nb < 4; ++nb) {
                int d = nb * 32 + iln;
                int byte = d * 128 + 16 * ((kk2 * 2 + h) ^ (d & 7));
                bf16x8 vf = *(const bf16x8*)(Vb + byte);
                accO[nb] = __builtin_amdgcn_mfma_f32_32x32x16_bf16(af, vf, accO[nb], 0, 0, 0);
            }
        }
        __builtin_amdgcn_s_setprio(0);

        asm volatile("" ::: "memory");
        __builtin_amdgcn_s_barrier();
    }

    const int b = bh >> 4, hh = bh & 15;
    float invl = 1.f / l_r;
#pragma unroll
    for (int reg = 0; reg < 16; ++reg) {
        int rrow = (reg & 3) + 8 * (reg >> 2) + 4 * h;
        float iv = __shfl(invl, rrow, 64);
        int t = qb * 128 + wave * 32 + rrow;
        long base = ((long)(b * Tt + t) * Hh + hh) * Dd;
#pragma unroll
        for (int nb = 0; nb < 4; ++nb)
            o[base + nb * 32 + iln] = f2bf(accO[nb][reg] * iv);
    }
}

// ---------------------------------------------------------------- output projection GEMM
// (R3-proven 16x16 structure: dbuf 64KB, counted vmcnt, low-conflict reads)
__global__ __launch_bounds__(256) void out_gemm(
    const unsigned short* __restrict__ oIn,
    const unsigned short* __restrict__ woT,
    float* __restrict__ out) {
    __shared__ __align__(16) unsigned short smem[32768];
    const int bm = blockIdx.x, bn = blockIdx.y;
    const int tid = threadIdx.x;
    const int lane = tid & 63;
    const int wave = tid >> 6;
    const int g = lane >> 4;
    const int ln = lane & 15;

    const unsigned short* arow = oIn + (long)bm * 128 * Mm;
    const unsigned short* brow = woT + (long)bn * 128 * Mm;

    f32x4 acc[2][8];
#pragma unroll
    for (int a = 0; a < 2; ++a)
#pragma unroll
        for (int b2 = 0; b2 < 8; ++b2)
#pragma unroll
            for (int e = 0; e < 4; ++e) acc[a][b2][e] = 0.f;

    auto stage = [&](int buf, int kt) {
        const int k0 = kt * 64;
#pragma unroll
        for (int it = 0; it < 4; ++it) {
            int f = it * 256 + tid;
            int r = f >> 3, c = f & 7;
            long off = (long)r * Mm + k0 + ((c ^ (r & 7)) << 3);
            gld16(arow + off, (char*)smem + buf * 32768 + f * 16);
            gld16(brow + off, (char*)smem + buf * 32768 + 16384 + f * 16);
        }
    };

    stage(0, 0);

    for (int kt = 0; kt < Mm / 64; ++kt) {
        const int cur = kt & 1;
        if (kt + 1 < Mm / 64) {
            stage(cur ^ 1, kt + 1);
            asm volatile("s_waitcnt vmcnt(8)" ::: "memory");
        } else {
            asm volatile("s_waitcnt vmcnt(0)" ::: "memory");
        }
        __builtin_amdgcn_s_barrier();

        const char* Ab = (const char*)smem + cur * 32768;
        const char* Bv = Ab + 16384;
#pragma unroll
        for (int kc = 0; kc < 2; ++kc) {
            bf16x8 af[2];
#pragma unroll
            for (int rf = 0; rf < 2; ++rf) {
                int row = wave * 32 + rf * 16 + ln;
                int byte = (row * 128 + kc * 64 + g * 16) ^ ((row & 7) << 4);
                af[rf] = *(const bf16x8*)(Ab + byte);
            }
#pragma unroll
            for (int ni = 0; ni < 8; ++ni) {
                int row = ni * 16 + ln;
                int byte = (row * 128 + kc * 64 + g * 16) ^ ((row & 7) << 4);
                bf16x8 bfv = *(const bf16x8*)(Bv + byte);
#pragma unroll
                for (int rf = 0; rf < 2; ++rf)
                    acc[rf][ni] = __builtin_amdgcn_mfma_f32_16x16x32_bf16(af[rf], bfv, acc[rf][ni], 0, 0, 0);
            }
        }
        asm volatile("" ::: "memory");
        __builtin_amdgcn_s_barrier();
    }

#pragma unroll
    for (int rf = 0; rf < 2; ++rf)
#pragma unroll
        for (int reg = 0; reg < 4; ++reg) {
            long row = bm * 128 + wave * 32 + rf * 16 + g * 4 + reg;
#pragma unroll
            for (int ni = 0; ni < 8; ++ni)
                out[row * Mm + bn * 128 + ni * 16 + ln] = acc[rf][ni][reg];
        }
}

// ---------------------------------------------------------------- launch

extern "C" void kernel_launch(void* const* d_in, const int* in_sizes, int n_in,
                              void* d_out, int out_size, void* d_ws, size_t ws_size,
                              hipStream_t stream) {
    const float* x    = (const float*)d_in[0];
    const float* w_aq = (const float*)d_in[1];
    const float* w_ak = (const float*)d_in[2];
    const float* w_av = (const float*)d_in[3];
    const float* w_ao = (const float*)d_in[4];
    float* out = (float*)d_out;

    char* ws = (char*)d_ws;
    const long SZ_BTM = 16777216;   // B*T*M * 2B
    const long SZ_W   = 8388608;    // 2048*2048 * 2B
    unsigned short* xb2 = (unsigned short*)(ws);
    unsigned short* qB  = (unsigned short*)(ws + SZ_BTM);
    unsigned short* kB  = (unsigned short*)(ws + 2 * SZ_BTM);
    unsigned short* vtB = (unsigned short*)(ws + 3 * SZ_BTM);
    unsigned short* oB  = (unsigned short*)(ws + 4 * SZ_BTM);
    unsigned short* wT2 = (unsigned short*)(ws + 5 * SZ_BTM);             // 24MB tiled qkv
    unsigned short* woT = (unsigned short*)(ws + 5 * SZ_BTM + 3 * SZ_W);
    float* cosT = (float*)(ws + 5 * SZ_BTM + 4 * SZ_W);
    float* sinT = (float*)(ws + 5 * SZ_BTM + 4 * SZ_W + 524288);

    cvt_x2<<<1024, 256, 0, stream>>>(x, xb2);
    w_qkv_tile<<<dim3(32, 48), 256, 0, stream>>>(w_aq, w_ak, w_av, wT2);
    transpose_cvt<<<dim3(64, 64, 1), 256, 0, stream>>>(w_ao, woT, 2048, 2048, 0, 0);
    rope_tab<<<512, 256, 0, stream>>>(cosT, sinT);

    proj_gemm5<<<dim3(32, 24), 256, 0, stream>>>(xb2, wT2, qB, kB, vtB, cosT, sinT);
    attn_kernel<<<dim3(512), 256, 0, stream>>>(qB, kB, vtB, oB);
    out_gemm<<<dim3(32, 16), 256, 0, stream>>>(oB, woT, out);
}

// Round 9
// 257.113 us; speedup vs baseline: 1.0746x; 1.0343x over previous
//
#include <hip/hip_runtime.h>

#define Bb 2
#define Tt 2048
#define Mm 2048
#define Hh 16
#define Dd 128

typedef __attribute__((ext_vector_type(8))) short bf16x8;
typedef __attribute__((ext_vector_type(4))) float f32x4;
typedef __attribute__((ext_vector_type(16))) float f32x16;

__device__ __forceinline__ unsigned short f2bf(float f) {
    unsigned int u = __builtin_bit_cast(unsigned int, f);
    u += 0x7FFFu + ((u >> 16) & 1u);   // RNE
    return (unsigned short)(u >> 16);
}

__device__ __forceinline__ unsigned int cvt_pk_bf16(float lo, float hi) {
    unsigned int r;
    asm("v_cvt_pk_bf16_f32 %0, %1, %2" : "=v"(r) : "v"(lo), "v"(hi));
    return r;
}

__device__ __forceinline__ float fexp2(float x) { return __builtin_amdgcn_exp2f(x); }

__device__ __forceinline__ void gld16(const void* g, void* l) {
    __builtin_amdgcn_global_load_lds(
        (const __attribute__((address_space(1))) void*)g,
        (__attribute__((address_space(3))) void*)l, 16, 0, 0);
}

// ---------------------------------------------------------------- prep kernels

// x (4096 x 2048 fp32) -> xb2 fragment-tiled bf16
__global__ __launch_bounds__(256) void cvt_x2(const float* __restrict__ x,
                                              unsigned short* __restrict__ xb2) {
    const int blk = blockIdx.x;              // 1024 = 32 mt x 32 kt
    const int mt = blk >> 5, kt = blk & 31;
#pragma unroll
    for (int it = 0; it < 4; ++it) {
        int s = it * 256 + threadIdx.x;
        int row = ((s >> 6) & 3) * 32 + (s & 31);
        int k = (s >> 8) * 16 + ((s >> 5) & 1) * 8;
        const float* sp = x + ((long)(mt * 128 + row)) * 2048 + kt * 64 + k;
        float4 a = *(const float4*)sp;
        float4 b = *(const float4*)(sp + 4);
        uint4 pk;
        pk.x = (unsigned int)f2bf(a.x) | ((unsigned int)f2bf(a.y) << 16);
        pk.y = (unsigned int)f2bf(a.z) | ((unsigned int)f2bf(a.w) << 16);
        pk.z = (unsigned int)f2bf(b.x) | ((unsigned int)f2bf(b.y) << 16);
        pk.w = (unsigned int)f2bf(b.z) | ((unsigned int)f2bf(b.w) << 16);
        *(uint4*)(xb2 + (((long)(mt * 32 + kt)) * 1024 + s) * 8) = pk;
    }
}

// qkv weights (H,M,D fp32) -> fragment-tiled bf16 with RoPE column permutation.
__global__ __launch_bounds__(256) void w_qkv_tile(
    const float* __restrict__ wq, const float* __restrict__ wk, const float* __restrict__ wv,
    unsigned short* __restrict__ outBase) {
    __shared__ float tile[64][132];
    const int kt = blockIdx.x;               // 0..31
    const int zy = blockIdx.y;               // 0..47
    const int which = zy >> 4, head = zy & 15;
    const float* src = (which == 0 ? wq : which == 1 ? wk : wv) + (long)head * 2048 * 128;
    const int tid = threadIdx.x;
#pragma unroll
    for (int it = 0; it < 8; ++it) {
        int f = it * 256 + tid;              // 2048 float4s = 64 rows x 32
        int row = f >> 5, c4 = f & 31;
        float4 v = *(const float4*)(src + (long)(kt * 64 + row) * 128 + c4 * 4);
        tile[row][c4 * 4 + 0] = v.x;
        tile[row][c4 * 4 + 1] = v.y;
        tile[row][c4 * 4 + 2] = v.z;
        tile[row][c4 * 4 + 3] = v.w;
    }
    __syncthreads();
    const int ntile = head >> 1, wn = head & 1;
    unsigned short* outp = outBase + (long)which * 4194304 +
                           ((long)(ntile * 32 + kt)) * 2048 * 8;
#pragma unroll
    for (int it = 0; it < 4; ++it) {
        int up = it * 256 + tid;
        int kk = up >> 8, nf = (up >> 6) & 3, l = up & 63;
        int il = l & 31, hl = l >> 5;
        int d = il + 64 * (nf & 1) + 32 * (nf >> 1);
        int kl = kk * 16 + hl * 8;
        uint4 pk;
        pk.x = (unsigned int)f2bf(tile[kl + 0][d]) | ((unsigned int)f2bf(tile[kl + 1][d]) << 16);
        pk.y = (unsigned int)f2bf(tile[kl + 2][d]) | ((unsigned int)f2bf(tile[kl + 3][d]) << 16);
        pk.z = (unsigned int)f2bf(tile[kl + 4][d]) | ((unsigned int)f2bf(tile[kl + 5][d]) << 16);
        pk.w = (unsigned int)f2bf(tile[kl + 6][d]) | ((unsigned int)f2bf(tile[kl + 7][d]) << 16);
        int u = kk * 512 + (wn * 4 + nf) * 64 + l;
        *(uint4*)(outp + (long)u * 8) = pk;
    }
}

// plain transpose (for w_ao): in rows x cols fp32 -> out cols x rows bf16
__global__ __launch_bounds__(256) void transpose_cvt(const float* __restrict__ in,
                                                     unsigned short* __restrict__ out,
                                                     int rows, int cols,
                                                     long in_slab, long out_slab) {
    __shared__ float tile[32][33];
    const float* ip = in + (long)blockIdx.z * in_slab;
    unsigned short* op = out + (long)blockIdx.z * out_slab;
    int r0 = blockIdx.x * 32, c0 = blockIdx.y * 32;
    int tx = threadIdx.x & 31, ty = threadIdx.x >> 5;
#pragma unroll
    for (int j = 0; j < 32; j += 8)
        tile[ty + j][tx] = ip[(long)(r0 + ty + j) * cols + c0 + tx];
    __syncthreads();
#pragma unroll
    for (int j = 0; j < 32; j += 8)
        op[(long)(c0 + ty + j) * rows + r0 + tx] = f2bf(tile[tx][ty + j]);
}

__global__ __launch_bounds__(256) void rope_tab(float* __restrict__ cosT,
                                                float* __restrict__ sinT) {
    int idx = blockIdx.x * 256 + threadIdx.x;   // T*64
    int t = idx >> 6, d = idx & 63;
    float freq = powf(10000.f, -(float)d / 64.f);
    float ang = (float)t * freq;
    sinT[idx] = sinf(ang);
    cosT[idx] = cosf(ang);
}

// ---------------------------------------------------------------- QKV projection GEMM
// 128x256 tile, 4 waves (2M x 2N), per-wave 64x128, 32x32x16 MFMA, BK=32.
// Fragment-major LDS (zero-conflict), 3 rotating buffers, DISTANCE-2 prefetch
// with counted vmcnt(12), bijective XCD swizzle (3 bn-panels per XCD -> B L2-hot).
__global__ __launch_bounds__(256, 2) void proj_gemm6(
    const unsigned short* __restrict__ xb2,
    const unsigned short* __restrict__ wT2,
    unsigned short* __restrict__ qO,
    unsigned short* __restrict__ kO,
    unsigned short* __restrict__ vtO,
    const float* __restrict__ cosT,
    const float* __restrict__ sinT) {
    __shared__ __align__(16) char lds[73728];   // 3 bufs x 24KB: A 8KB, B 16KB @+8192
    // XCD swizzle: dispatch d -> xcd=d%8 (HW round-robin); give each XCD a
    // contiguous orig-chunk of 96 = 3 full bn panels (bm fastest in orig).
    const int d = (int)blockIdx.x;              // 0..767
    const int orig = (d & 7) * 96 + (d >> 3);
    const int bm = orig & 31;                    // 0..31 over M=4096
    const int bn = orig >> 5;                    // 0..23 over N=6144
    const int mode = bn >> 3, ntile = bn & 7;
    const unsigned short* Asrc = xb2 + ((long)bm * 32) * 1024 * 8;
    const unsigned short* Bsrc = wT2 + (long)mode * 4194304 + ((long)ntile * 32) * 2048 * 8;

    const int tid = threadIdx.x, lane = tid & 63, wave = tid >> 6;
    const int il = lane & 31, hl = lane >> 5;
    const int wm = wave >> 1, wn = wave & 1;

    f32x16 acc[2][4];
#pragma unroll
    for (int a = 0; a < 2; ++a)
#pragma unroll
        for (int b2 = 0; b2 < 4; ++b2)
#pragma unroll
            for (int e = 0; e < 16; ++e) acc[a][b2][e] = 0.f;

    // stage half-K-tile kt2 (32 k) into buffer buf: A 512 chunks, B 1024 chunks (6 loads/thread)
    auto stage = [&](int buf, int kt2) {
        const int kt = kt2 >> 1, hf = kt2 & 1;
        const unsigned short* A0 = Asrc + ((long)kt * 1024 + hf * 512) * 8;
        const unsigned short* B0 = Bsrc + ((long)kt * 2048 + hf * 1024) * 8;
        char* dst = lds + buf * 24576;
#pragma unroll
        for (int l = 0; l < 2; ++l) {
            int s = l * 256 + tid;
            gld16(A0 + (long)s * 8, dst + s * 16);
        }
#pragma unroll
        for (int l = 0; l < 4; ++l) {
            int u = l * 256 + tid;
            gld16(B0 + (long)u * 8, dst + 8192 + u * 16);
        }
    };

    stage(0, 0);
    stage(1, 1);

    int cur = 0;
    for (int kt2 = 0; kt2 < 64; ++kt2) {
        int pre = cur + 2; if (pre >= 3) pre -= 3;
        if (kt2 + 2 < 64) {
            stage(pre, kt2 + 2);
            asm volatile("s_waitcnt vmcnt(12)" ::: "memory");   // buffer cur landed
        } else if (kt2 + 1 < 64) {
            asm volatile("s_waitcnt vmcnt(6)" ::: "memory");
        } else {
            asm volatile("s_waitcnt vmcnt(0)" ::: "memory");
        }
        __builtin_amdgcn_s_barrier();

        const char* bc = lds + cur * 24576;
#pragma unroll
        for (int kk2 = 0; kk2 < 2; ++kk2) {
            bf16x8 af[2], bf[4];
#pragma unroll
            for (int mf = 0; mf < 2; ++mf)
                af[mf] = *(const bf16x8*)(bc + (kk2 * 256 + (wm * 2 + mf) * 64 + lane) * 16);
#pragma unroll
            for (int nf = 0; nf < 4; ++nf)
                bf[nf] = *(const bf16x8*)(bc + 8192 + (kk2 * 512 + (wn * 4 + nf) * 64 + lane) * 16);
            __builtin_amdgcn_s_setprio(1);
#pragma unroll
            for (int mf = 0; mf < 2; ++mf)
#pragma unroll
                for (int nf = 0; nf < 4; ++nf)
                    acc[mf][nf] = __builtin_amdgcn_mfma_f32_32x32x16_bf16(af[mf], bf[nf], acc[mf][nf], 0, 0, 0);
            __builtin_amdgcn_s_setprio(0);
        }
        asm volatile("" ::: "memory");
        __builtin_amdgcn_s_barrier();
        cur = (cur == 2) ? 0 : cur + 1;
    }

    const int b = bm >> 4;
    const int t0 = (bm & 15) * 128;
    const int head = ntile * 2 + wn;    // wave owns one full head (128 cols)

    if (mode < 2) {
        const float qs = (mode == 0) ? 0.011271055f : 1.0f;  // log2(e)/D folded into q
        unsigned short* outp = (mode == 0) ? qO : kO;
        long hb = ((long)(b * Hh + head)) * Tt;
#pragma unroll
        for (int mf = 0; mf < 2; ++mf)
#pragma unroll
            for (int np = 0; np < 2; ++np) {       // nf pairs (0,1)=d[0,32), (2,3)=d[32,64)
                int d_lo = il + 32 * np;
#pragma unroll
                for (int reg = 0; reg < 16; ++reg) {
                    int r = (reg & 3) + 8 * (reg >> 2) + 4 * hl;
                    int t = t0 + wm * 64 + mf * 32 + r;
                    float c = cosT[t * 64 + d_lo], s = sinT[t * 64 + d_lo];
                    float ev = acc[mf][np * 2][reg], od = acc[mf][np * 2 + 1][reg];
                    long base = (hb + t) * Dd;
                    outp[base + d_lo]      = f2bf((ev * c - od * s) * qs);
                    outp[base + d_lo + 64] = f2bf((ev * s + od * c) * qs);
                }
            }
    } else {
        // V transposed out: per-wave 8KB patch per mf half (128 dslot x 32 t)
        char* patch = lds + wave * 8192;
        long hdbase = ((long)(b * Hh + head)) * Dd;
#pragma unroll
        for (int mf = 0; mf < 2; ++mf) {
#pragma unroll
            for (int nf = 0; nf < 4; ++nf) {
                int dslot = nf * 32 + il;
                int swz = (dslot & 3) << 4;
#pragma unroll
                for (int qg = 0; qg < 4; ++qg) {
                    uint2 w;
                    w.x = cvt_pk_bf16(acc[mf][nf][qg * 4 + 0], acc[mf][nf][qg * 4 + 1]);
                    w.y = cvt_pk_bf16(acc[mf][nf][qg * 4 + 2], acc[mf][nf][qg * 4 + 3]);
                    *(uint2*)(patch + dslot * 64 + ((qg * 16 + hl * 8) ^ swz)) = w;
                }
            }
            __builtin_amdgcn_s_waitcnt(0);  // lgkm drain (same-wave write->read)
#pragma unroll
            for (int p = 0; p < 8; ++p) {
                int dslot = p * 16 + (lane >> 2);
                int t8 = lane & 3;
                uint4 v = *(const uint4*)(patch + dslot * 64 + ((t8 * 16) ^ ((dslot & 3) << 4)));
                int ordv = dslot >> 5, il2 = dslot & 31;
                int dd = il2 + 32 * (ordv >> 1) + 64 * (ordv & 1);
                int tg = t0 + wm * 64 + mf * 32 + t8 * 8;
                *(uint4*)(vtO + (hdbase + dd) * Tt + tg) = v;
            }
            __builtin_amdgcn_s_waitcnt(0);
        }
    }
}

// ---------------------------------------------------------------- flash attention (swapped QK^T, 32x32x16)
__global__ __launch_bounds__(256) void attn_kernel(
    const unsigned short* __restrict__ q,
    const unsigned short* __restrict__ k,
    const unsigned short* __restrict__ vt,
    unsigned short* __restrict__ o) {
    __shared__ __align__(16) unsigned short lds[32768];

    const int lid = (int)blockIdx.x;
    const int p = lid & 255;
    const int bh = p & 31;
    const int q0 = p >> 5;
    const int qb = (lid >> 8) ? (15 - q0) : q0;

    const int tid = threadIdx.x, lane = tid & 63, wave = tid >> 6;
    const int h = lane >> 5, iln = lane & 31;

    const unsigned short* qp = q + (long)bh * Tt * Dd;
    const unsigned short* kp = k + (long)bh * Tt * Dd;
    const unsigned short* vp = vt + (long)bh * Dd * Tt;

    const int i_g = qb * 128 + wave * 32 + iln;
    bf16x8 qf[8];
#pragma unroll
    for (int kk = 0; kk < 8; ++kk)
        qf[kk] = *(const bf16x8*)(qp + (long)i_g * Dd + kk * 16 + h * 8);

    f32x16 accO[4];
#pragma unroll
    for (int nb = 0; nb < 4; ++nb)
#pragma unroll
        for (int e = 0; e < 16; ++e) accO[nb][e] = 0.f;

    float m_r = -1e30f, l_r = 0.f;
    const int ntiles = 2 * qb + 2;

    auto stage = [&](int buf, int tix) {
        const int j0s = tix * 64;
#pragma unroll
        for (int it = 0; it < 4; ++it) {
            int f = it * 256 + tid;
            int rk = f >> 4, ck = f & 15;
            gld16(kp + ((long)(j0s + rk) * Dd + ((ck ^ (rk & 7)) << 3)),
                  (char*)lds + buf * 16384 + f * 16);
            int rv = f >> 3, cv = f & 7;
            gld16(vp + ((long)rv * Tt + j0s + ((cv ^ (rv & 7)) << 3)),
                  (char*)lds + 32768 + buf * 16384 + f * 16);
        }
    };

    stage(0, 0);

    for (int tix = 0; tix < ntiles; ++tix) {
        const int cur = tix & 1;
        const int j0 = tix * 64;
        if (tix + 1 < ntiles) {
            stage(cur ^ 1, tix + 1);
            asm volatile("s_waitcnt vmcnt(8)" ::: "memory");
        } else {
            asm volatile("s_waitcnt vmcnt(0)" ::: "memory");
        }
        __builtin_amdgcn_s_barrier();

        const char* Kb = (const char*)lds + cur * 16384;
        const char* Vb = (const char*)lds + 32768 + cur * 16384;

        f32x16 sacc[2];
#pragma unroll
        for (int mb = 0; mb < 2; ++mb)
#pragma unroll
            for (int e = 0; e < 16; ++e) sacc[mb][e] = 0.f;

        __builtin_amdgcn_s_setprio(1);
#pragma unroll
        for (int mb = 0; mb < 2; ++mb) {
            int row = mb * 32 + iln;
            const char* Kr = Kb + row * 256;
            int sw = row & 7;
#pragma unroll
            for (int kk = 0; kk < 8; ++kk) {
                bf16x8 kf = *(const bf16x8*)(Kr + 16 * ((kk * 2 + h) ^ sw));
                sacc[mb] = __builtin_amdgcn_mfma_f32_32x32x16_bf16(kf, qf[kk], sacc[mb], 0, 0, 0);
            }
        }
        __builtin_amdgcn_s_setprio(0);

        const bool domask = (j0 + 63 > qb * 128);
        if (domask) {
#pragma unroll
            for (int mb = 0; mb < 2; ++mb)
#pragma unroll
                for (int reg = 0; reg < 16; ++reg) {
                    int j = j0 + mb * 32 + (reg & 3) + 8 * (reg >> 2) + 4 * h;
                    if (j > i_g) sacc[mb][reg] = -1e30f;
                }
        }

        float red[16];
#pragma unroll
        for (int r = 0; r < 16; ++r) red[r] = fmaxf(sacc[0][r], sacc[1][r]);
#pragma unroll
        for (int s = 8; s >= 1; s >>= 1)
#pragma unroll
            for (int r = 0; r < s; ++r) red[r] = fmaxf(red[r], red[r + s]);
        float mx = fmaxf(red[0], __shfl_xor(red[0], 32, 64));

        if (__any(mx > m_r + 8.f)) {
            float mn = fmaxf(m_r, mx);
            float corr = fexp2(m_r - mn);
            m_r = mn;
            l_r *= corr;
#pragma unroll
            for (int reg = 0; reg < 16; ++reg) {
                int rrow = (reg & 3) + 8 * (reg >> 2) + 4 * h;
                float c = __shfl(corr, rrow, 64);
#pragma unroll
                for (int nb = 0; nb < 4; ++nb) accO[nb][reg] *= c;
            }
        }

        float pe[2][16];
#pragma unroll
        for (int mb = 0; mb < 2; ++mb)
#pragma unroll
            for (int r = 0; r < 16; ++r) pe[mb][r] = fexp2(sacc[mb][r] - m_r);
        float sr[16];
#pragma unroll
        for (int r = 0; r < 16; ++r) sr[r] = pe[0][r] + pe[1][r];
#pragma unroll
        for (int s = 8; s >= 1; s >>= 1)
#pragma unroll
            for (int r = 0; r < s; ++r) sr[r] += sr[r + s];
        l_r += sr[0] + __shfl_xor(sr[0], 32, 64);

        unsigned int pu[2][8];
#pragma unroll
        for (int mb = 0; mb < 2; ++mb)
#pragma unroll
            for (int t = 0; t < 8; ++t)
                pu[mb][t] = cvt_pk_bf16(pe[mb][2 * t], pe[mb][2 * t + 1]);

        unsigned int rv2[2][4];
#pragma unroll
        for (int mb = 0; mb < 2; ++mb)
#pragma unroll
            for (int u = 0; u < 4; ++u) {
                unsigned int sv = h ? pu[mb][(u & 1) + 4 * (u >> 1)]
                                    : pu[mb][2 + (u & 1) + 4 * (u >> 1)];
                rv2[mb][u] = __shfl_xor(sv, 32, 64);
            }

        __builtin_amdgcn_s_setprio(1);
#pragma unroll
        for (int kk2 = 0; kk2 < 4; ++kk2) {
            const int mb = kk2 >> 1, c2 = kk2 & 1;
            unsigned int w0 = h ? rv2[mb][2 * c2 + 0] : pu[mb][4 * c2 + 0];
            unsigned int w1 = h ? rv2[mb][2 * c2 + 1] : pu[mb][4 * c2 + 1];
            unsigned int w2 = h ? pu[mb][4 * c2 + 2] : rv2[mb][2 * c2 + 0];
            unsigned int w3 = h ? pu[mb][4 * c2 + 3] : rv2[mb][2 * c2 + 1];
            uint4 aw; aw.x = w0; aw.y = w1; aw.z = w2; aw.w = w3;
            bf16x8 af = __builtin_bit_cast(bf16x8, aw);
#pragma unroll
            for (int nb = 0; nb < 4; ++nb) {
                int dd = nb * 32 + iln;
                int byte = dd * 128 + 16 * ((kk2 * 2 + h) ^ (dd & 7));
                bf16x8 vf = *(const bf16x8*)(Vb + byte);
                accO[nb] = __builtin_amdgcn_mfma_f32_32x32x16_bf16(af, vf, accO[nb], 0, 0, 0);
            }
        }
        __builtin_amdgcn_s_setprio(0);

        asm volatile("" ::: "memory");
        __builtin_amdgcn_s_barrier();
    }

    const int b = bh >> 4, hh = bh & 15;
    float invl = 1.f / l_r;
#pragma unroll
    for (int reg = 0; reg < 16; ++reg) {
        int rrow = (reg & 3) + 8 * (reg >> 2) + 4 * h;
        float iv = __shfl(invl, rrow, 64);
        int t = qb * 128 + wave * 32 + rrow;
        long base = ((long)(b * Tt + t) * Hh + hh) * Dd;
#pragma unroll
        for (int nb = 0; nb < 4; ++nb)
            o[base + nb * 32 + iln] = f2bf(accO[nb][reg] * iv);
    }
}

// ---------------------------------------------------------------- output projection GEMM
__global__ __launch_bounds__(256) void out_gemm(
    const unsigned short* __restrict__ oIn,
    const unsigned short* __restrict__ woT,
    float* __restrict__ out) {
    __shared__ __align__(16) unsigned short smem[32768];
    const int bm = blockIdx.x, bn = blockIdx.y;
    const int tid = threadIdx.x;
    const int lane = tid & 63;
    const int wave = tid >> 6;
    const int g = lane >> 4;
    const int ln = lane & 15;

    const unsigned short* arow = oIn + (long)bm * 128 * Mm;
    const unsigned short* brow = woT + (long)bn * 128 * Mm;

    f32x4 acc[2][8];
#pragma unroll
    for (int a = 0; a < 2; ++a)
#pragma unroll
        for (int b2 = 0; b2 < 8; ++b2)
#pragma unroll
            for (int e = 0; e < 4; ++e) acc[a][b2][e] = 0.f;

    auto stage = [&](int buf, int kt) {
        const int k0 = kt * 64;
#pragma unroll
        for (int it = 0; it < 4; ++it) {
            int f = it * 256 + tid;
            int r = f >> 3, c = f & 7;
            long off = (long)r * Mm + k0 + ((c ^ (r & 7)) << 3);
            gld16(arow + off, (char*)smem + buf * 32768 + f * 16);
            gld16(brow + off, (char*)smem + buf * 32768 + 16384 + f * 16);
        }
    };

    stage(0, 0);

    for (int kt = 0; kt < Mm / 64; ++kt) {
        const int cur = kt & 1;
        if (kt + 1 < Mm / 64) {
            stage(cur ^ 1, kt + 1);
            asm volatile("s_waitcnt vmcnt(8)" ::: "memory");
        } else {
            asm volatile("s_waitcnt vmcnt(0)" ::: "memory");
        }
        __builtin_amdgcn_s_barrier();

        const char* Ab = (const char*)smem + cur * 32768;
        const char* Bv = Ab + 16384;
#pragma unroll
        for (int kc = 0; kc < 2; ++kc) {
            bf16x8 af[2];
#pragma unroll
            for (int rf = 0; rf < 2; ++rf) {
                int row = wave * 32 + rf * 16 + ln;
                int byte = (row * 128 + kc * 64 + g * 16) ^ ((row & 7) << 4);
                af[rf] = *(const bf16x8*)(Ab + byte);
            }
#pragma unroll
            for (int ni = 0; ni < 8; ++ni) {
                int row = ni * 16 + ln;
                int byte = (row * 128 + kc * 64 + g * 16) ^ ((row & 7) << 4);
                bf16x8 bfv = *(const bf16x8*)(Bv + byte);
#pragma unroll
                for (int rf = 0; rf < 2; ++rf)
                    acc[rf][ni] = __builtin_amdgcn_mfma_f32_16x16x32_bf16(af[rf], bfv, acc[rf][ni], 0, 0, 0);
            }
        }
        asm volatile("" ::: "memory");
        __builtin_amdgcn_s_barrier();
    }

#pragma unroll
    for (int rf = 0; rf < 2; ++rf)
#pragma unroll
        for (int reg = 0; reg < 4; ++reg) {
            long row = bm * 128 + wave * 32 + rf * 16 + g * 4 + reg;
#pragma unroll
            for (int ni = 0; ni < 8; ++ni)
                out[row * Mm + bn * 128 + ni * 16 + ln] = acc[rf][ni][reg];
        }
}

// ---------------------------------------------------------------- launch

extern "C" void kernel_launch(void* const* d_in, const int* in_sizes, int n_in,
                              void* d_out, int out_size, void* d_ws, size_t ws_size,
                              hipStream_t stream) {
    const float* x    = (const float*)d_in[0];
    const float* w_aq = (const float*)d_in[1];
    const float* w_ak = (const float*)d_in[2];
    const float* w_av = (const float*)d_in[3];
    const float* w_ao = (const float*)d_in[4];
    float* out = (float*)d_out;

    char* ws = (char*)d_ws;
    const long SZ_BTM = 16777216;   // B*T*M * 2B
    const long SZ_W   = 8388608;    // 2048*2048 * 2B
    unsigned short* xb2 = (unsigned short*)(ws);
    unsigned short* qB  = (unsigned short*)(ws + SZ_BTM);
    unsigned short* kB  = (unsigned short*)(ws + 2 * SZ_BTM);
    unsigned short* vtB = (unsigned short*)(ws + 3 * SZ_BTM);
    unsigned short* oB  = (unsigned short*)(ws + 4 * SZ_BTM);
    unsigned short* wT2 = (unsigned short*)(ws + 5 * SZ_BTM);             // 24MB tiled qkv
    unsigned short* woT = (unsigned short*)(ws + 5 * SZ_BTM + 3 * SZ_W);
    float* cosT = (float*)(ws + 5 * SZ_BTM + 4 * SZ_W);
    float* sinT = (float*)(ws + 5 * SZ_BTM + 4 * SZ_W + 524288);

    cvt_x2<<<1024, 256, 0, stream>>>(x, xb2);
    w_qkv_tile<<<dim3(32, 48), 256, 0, stream>>>(w_aq, w_ak, w_av, wT2);
    transpose_cvt<<<dim3(64, 64, 1), 256, 0, stream>>>(w_ao, woT, 2048, 2048, 0, 0);
    rope_tab<<<512, 256, 0, stream>>>(cosT, sinT);

    proj_gemm6<<<dim3(768), 256, 0, stream>>>(xb2, wT2, qB, kB, vtB, cosT, sinT);
    attn_kernel<<<dim3(512), 256, 0, stream>>>(qB, kB, vtB, oB);
    out_gemm<<<dim3(32, 16), 256, 0, stream>>>(oB, woT, out);
}

// Round 10
// 254.047 us; speedup vs baseline: 1.0876x; 1.0121x over previous
//
#include <hip/hip_runtime.h>

#define Bb 2
#define Tt 2048
#define Mm 2048
#define Hh 16
#define Dd 128

typedef __attribute__((ext_vector_type(8))) short bf16x8;
typedef __attribute__((ext_vector_type(4))) float f32x4;
typedef __attribute__((ext_vector_type(16))) float f32x16;

__device__ __forceinline__ unsigned short f2bf(float f) {
    unsigned int u = __builtin_bit_cast(unsigned int, f);
    u += 0x7FFFu + ((u >> 16) & 1u);   // RNE
    return (unsigned short)(u >> 16);
}

__device__ __forceinline__ unsigned int cvt_pk_bf16(float lo, float hi) {
    unsigned int r;
    asm("v_cvt_pk_bf16_f32 %0, %1, %2" : "=v"(r) : "v"(lo), "v"(hi));
    return r;
}

__device__ __forceinline__ float fexp2(float x) { return __builtin_amdgcn_exp2f(x); }

__device__ __forceinline__ void gld16(const void* g, void* l) {
    __builtin_amdgcn_global_load_lds(
        (const __attribute__((address_space(1))) void*)g,
        (__attribute__((address_space(3))) void*)l, 16, 0, 0);
}

// ---------------------------------------------------------------- prep kernels

// x (4096 x 2048 fp32) -> xb2 fragment-tiled bf16
__global__ __launch_bounds__(256) void cvt_x2(const float* __restrict__ x,
                                              unsigned short* __restrict__ xb2) {
    const int blk = blockIdx.x;              // 1024 = 32 mt x 32 kt
    const int mt = blk >> 5, kt = blk & 31;
#pragma unroll
    for (int it = 0; it < 4; ++it) {
        int s = it * 256 + threadIdx.x;
        int row = ((s >> 6) & 3) * 32 + (s & 31);
        int k = (s >> 8) * 16 + ((s >> 5) & 1) * 8;
        const float* sp = x + ((long)(mt * 128 + row)) * 2048 + kt * 64 + k;
        float4 a = *(const float4*)sp;
        float4 b = *(const float4*)(sp + 4);
        uint4 pk;
        pk.x = (unsigned int)f2bf(a.x) | ((unsigned int)f2bf(a.y) << 16);
        pk.y = (unsigned int)f2bf(a.z) | ((unsigned int)f2bf(a.w) << 16);
        pk.z = (unsigned int)f2bf(b.x) | ((unsigned int)f2bf(b.y) << 16);
        pk.w = (unsigned int)f2bf(b.z) | ((unsigned int)f2bf(b.w) << 16);
        *(uint4*)(xb2 + (((long)(mt * 32 + kt)) * 1024 + s) * 8) = pk;
    }
}

// qkv weights (H,M,D fp32) -> fragment-tiled bf16 with RoPE column permutation.
__global__ __launch_bounds__(256) void w_qkv_tile(
    const float* __restrict__ wq, const float* __restrict__ wk, const float* __restrict__ wv,
    unsigned short* __restrict__ outBase) {
    __shared__ float tile[64][132];
    const int kt = blockIdx.x;               // 0..31
    const int zy = blockIdx.y;               // 0..47
    const int which = zy >> 4, head = zy & 15;
    const float* src = (which == 0 ? wq : which == 1 ? wk : wv) + (long)head * 2048 * 128;
    const int tid = threadIdx.x;
#pragma unroll
    for (int it = 0; it < 8; ++it) {
        int f = it * 256 + tid;              // 2048 float4s = 64 rows x 32
        int row = f >> 5, c4 = f & 31;
        float4 v = *(const float4*)(src + (long)(kt * 64 + row) * 128 + c4 * 4);
        tile[row][c4 * 4 + 0] = v.x;
        tile[row][c4 * 4 + 1] = v.y;
        tile[row][c4 * 4 + 2] = v.z;
        tile[row][c4 * 4 + 3] = v.w;
    }
    __syncthreads();
    const int ntile = head >> 1, wn = head & 1;
    unsigned short* outp = outBase + (long)which * 4194304 +
                           ((long)(ntile * 32 + kt)) * 2048 * 8;
#pragma unroll
    for (int it = 0; it < 4; ++it) {
        int up = it * 256 + tid;
        int kk = up >> 8, nf = (up >> 6) & 3, l = up & 63;
        int il = l & 31, hl = l >> 5;
        int d = il + 64 * (nf & 1) + 32 * (nf >> 1);
        int kl = kk * 16 + hl * 8;
        uint4 pk;
        pk.x = (unsigned int)f2bf(tile[kl + 0][d]) | ((unsigned int)f2bf(tile[kl + 1][d]) << 16);
        pk.y = (unsigned int)f2bf(tile[kl + 2][d]) | ((unsigned int)f2bf(tile[kl + 3][d]) << 16);
        pk.z = (unsigned int)f2bf(tile[kl + 4][d]) | ((unsigned int)f2bf(tile[kl + 5][d]) << 16);
        pk.w = (unsigned int)f2bf(tile[kl + 6][d]) | ((unsigned int)f2bf(tile[kl + 7][d]) << 16);
        int u = kk * 512 + (wn * 4 + nf) * 64 + l;
        *(uint4*)(outp + (long)u * 8) = pk;
    }
}

// plain transpose (for w_ao): in rows x cols fp32 -> out cols x rows bf16
__global__ __launch_bounds__(256) void transpose_cvt(const float* __restrict__ in,
                                                     unsigned short* __restrict__ out,
                                                     int rows, int cols,
                                                     long in_slab, long out_slab) {
    __shared__ float tile[32][33];
    const float* ip = in + (long)blockIdx.z * in_slab;
    unsigned short* op = out + (long)blockIdx.z * out_slab;
    int r0 = blockIdx.x * 32, c0 = blockIdx.y * 32;
    int tx = threadIdx.x & 31, ty = threadIdx.x >> 5;
#pragma unroll
    for (int j = 0; j < 32; j += 8)
        tile[ty + j][tx] = ip[(long)(r0 + ty + j) * cols + c0 + tx];
    __syncthreads();
#pragma unroll
    for (int j = 0; j < 32; j += 8)
        op[(long)(c0 + ty + j) * rows + r0 + tx] = f2bf(tile[tx][ty + j]);
}

__global__ __launch_bounds__(256) void rope_tab(float* __restrict__ cosT,
                                                float* __restrict__ sinT) {
    int idx = blockIdx.x * 256 + threadIdx.x;   // T*64
    int t = idx >> 6, d = idx & 63;
    float freq = powf(10000.f, -(float)d / 64.f);
    float ang = (float)t * freq;
    sinT[idx] = sinf(ang);
    cosT[idx] = cosf(ang);
}

// ---------------------------------------------------------------- QKV projection GEMM
// 128x256 tile, 4 waves (2M x 2N), per-wave 64x128, 32x32x16 MFMA, BK=32.
// Fragment-major LDS (zero-conflict), 3 rotating buffers, DISTANCE-2 prefetch
// with counted vmcnt(12). NATURAL block order (R9's XCD remap scattered
// neighbors -> FETCH +53%; reverted).
__global__ __launch_bounds__(256, 2) void proj_gemm6(
    const unsigned short* __restrict__ xb2,
    const unsigned short* __restrict__ wT2,
    unsigned short* __restrict__ qO,
    unsigned short* __restrict__ kO,
    unsigned short* __restrict__ vtO,
    const float* __restrict__ cosT,
    const float* __restrict__ sinT) {
    __shared__ __align__(16) char lds[73728];   // 3 bufs x 24KB: A 8KB, B 16KB @+8192
    const int d = (int)blockIdx.x;              // 0..767, natural order (bm fastest)
    const int bm = d & 31;                       // 0..31 over M=4096
    const int bn = d >> 5;                       // 0..23 over N=6144
    const int mode = bn >> 3, ntile = bn & 7;
    const unsigned short* Asrc = xb2 + ((long)bm * 32) * 1024 * 8;
    const unsigned short* Bsrc = wT2 + (long)mode * 4194304 + ((long)ntile * 32) * 2048 * 8;

    const int tid = threadIdx.x, lane = tid & 63, wave = tid >> 6;
    const int il = lane & 31, hl = lane >> 5;
    const int wm = wave >> 1, wn = wave & 1;

    f32x16 acc[2][4];
#pragma unroll
    for (int a = 0; a < 2; ++a)
#pragma unroll
        for (int b2 = 0; b2 < 4; ++b2)
#pragma unroll
            for (int e = 0; e < 16; ++e) acc[a][b2][e] = 0.f;

    // stage half-K-tile kt2 (32 k) into buffer buf: A 512 chunks, B 1024 chunks (6 loads/thread)
    auto stage = [&](int buf, int kt2) {
        const int kt = kt2 >> 1, hf = kt2 & 1;
        const unsigned short* A0 = Asrc + ((long)kt * 1024 + hf * 512) * 8;
        const unsigned short* B0 = Bsrc + ((long)kt * 2048 + hf * 1024) * 8;
        char* dst = lds + buf * 24576;
#pragma unroll
        for (int l = 0; l < 2; ++l) {
            int s = l * 256 + tid;
            gld16(A0 + (long)s * 8, dst + s * 16);
        }
#pragma unroll
        for (int l = 0; l < 4; ++l) {
            int u = l * 256 + tid;
            gld16(B0 + (long)u * 8, dst + 8192 + u * 16);
        }
    };

    stage(0, 0);
    stage(1, 1);

    int cur = 0;
    for (int kt2 = 0; kt2 < 64; ++kt2) {
        int pre = cur + 2; if (pre >= 3) pre -= 3;
        if (kt2 + 2 < 64) {
            stage(pre, kt2 + 2);
            asm volatile("s_waitcnt vmcnt(12)" ::: "memory");   // buffer cur landed
        } else if (kt2 + 1 < 64) {
            asm volatile("s_waitcnt vmcnt(6)" ::: "memory");
        } else {
            asm volatile("s_waitcnt vmcnt(0)" ::: "memory");
        }
        __builtin_amdgcn_s_barrier();

        const char* bc = lds + cur * 24576;
#pragma unroll
        for (int kk2 = 0; kk2 < 2; ++kk2) {
            bf16x8 af[2], bf[4];
#pragma unroll
            for (int mf = 0; mf < 2; ++mf)
                af[mf] = *(const bf16x8*)(bc + (kk2 * 256 + (wm * 2 + mf) * 64 + lane) * 16);
#pragma unroll
            for (int nf = 0; nf < 4; ++nf)
                bf[nf] = *(const bf16x8*)(bc + 8192 + (kk2 * 512 + (wn * 4 + nf) * 64 + lane) * 16);
            __builtin_amdgcn_s_setprio(1);
#pragma unroll
            for (int mf = 0; mf < 2; ++mf)
#pragma unroll
                for (int nf = 0; nf < 4; ++nf)
                    acc[mf][nf] = __builtin_amdgcn_mfma_f32_32x32x16_bf16(af[mf], bf[nf], acc[mf][nf], 0, 0, 0);
            __builtin_amdgcn_s_setprio(0);
        }
        asm volatile("" ::: "memory");
        __builtin_amdgcn_s_barrier();
        cur = (cur == 2) ? 0 : cur + 1;
    }

    const int b = bm >> 4;
    const int t0 = (bm & 15) * 128;
    const int head = ntile * 2 + wn;    // wave owns one full head (128 cols)

    if (mode < 2) {
        const float qs = (mode == 0) ? 0.011271055f : 1.0f;  // log2(e)/D folded into q
        unsigned short* outp = (mode == 0) ? qO : kO;
        long hb = ((long)(b * Hh + head)) * Tt;
#pragma unroll
        for (int mf = 0; mf < 2; ++mf)
#pragma unroll
            for (int np = 0; np < 2; ++np) {       // nf pairs (0,1)=d[0,32), (2,3)=d[32,64)
                int d_lo = il + 32 * np;
#pragma unroll
                for (int reg = 0; reg < 16; ++reg) {
                    int r = (reg & 3) + 8 * (reg >> 2) + 4 * hl;
                    int t = t0 + wm * 64 + mf * 32 + r;
                    float c = cosT[t * 64 + d_lo], s = sinT[t * 64 + d_lo];
                    float ev = acc[mf][np * 2][reg], od = acc[mf][np * 2 + 1][reg];
                    long base = (hb + t) * Dd;
                    outp[base + d_lo]      = f2bf((ev * c - od * s) * qs);
                    outp[base + d_lo + 64] = f2bf((ev * s + od * c) * qs);
                }
            }
    } else {
        // V transposed out: per-wave 8KB patch per mf half (128 dslot x 32 t)
        char* patch = lds + wave * 8192;
        long hdbase = ((long)(b * Hh + head)) * Dd;
#pragma unroll
        for (int mf = 0; mf < 2; ++mf) {
#pragma unroll
            for (int nf = 0; nf < 4; ++nf) {
                int dslot = nf * 32 + il;
                int swz = (dslot & 3) << 4;
#pragma unroll
                for (int qg = 0; qg < 4; ++qg) {
                    uint2 w;
                    w.x = cvt_pk_bf16(acc[mf][nf][qg * 4 + 0], acc[mf][nf][qg * 4 + 1]);
                    w.y = cvt_pk_bf16(acc[mf][nf][qg * 4 + 2], acc[mf][nf][qg * 4 + 3]);
                    *(uint2*)(patch + dslot * 64 + ((qg * 16 + hl * 8) ^ swz)) = w;
                }
            }
            __builtin_amdgcn_s_waitcnt(0);  // lgkm drain (same-wave write->read)
#pragma unroll
            for (int p = 0; p < 8; ++p) {
                int dslot = p * 16 + (lane >> 2);
                int t8 = lane & 3;
                uint4 v = *(const uint4*)(patch + dslot * 64 + ((t8 * 16) ^ ((dslot & 3) << 4)));
                int ordv = dslot >> 5, il2 = dslot & 31;
                int dd = il2 + 32 * (ordv >> 1) + 64 * (ordv & 1);
                int tg = t0 + wm * 64 + mf * 32 + t8 * 8;
                *(uint4*)(vtO + (hdbase + dd) * Tt + tg) = v;
            }
            __builtin_amdgcn_s_waitcnt(0);
        }
    }
}

// ---------------------------------------------------------------- flash attention (swapped QK^T, 32x32x16)
__global__ __launch_bounds__(256) void attn_kernel(
    const unsigned short* __restrict__ q,
    const unsigned short* __restrict__ k,
    const unsigned short* __restrict__ vt,
    unsigned short* __restrict__ o) {
    __shared__ __align__(16) unsigned short lds[32768];

    const int lid = (int)blockIdx.x;
    const int p = lid & 255;
    const int bh = p & 31;
    const int q0 = p >> 5;
    const int qb = (lid >> 8) ? (15 - q0) : q0;

    const int tid = threadIdx.x, lane = tid & 63, wave = tid >> 6;
    const int h = lane >> 5, iln = lane & 31;

    const unsigned short* qp = q + (long)bh * Tt * Dd;
    const unsigned short* kp = k + (long)bh * Tt * Dd;
    const unsigned short* vp = vt + (long)bh * Dd * Tt;

    const int i_g = qb * 128 + wave * 32 + iln;
    bf16x8 qf[8];
#pragma unroll
    for (int kk = 0; kk < 8; ++kk)
        qf[kk] = *(const bf16x8*)(qp + (long)i_g * Dd + kk * 16 + h * 8);

    f32x16 accO[4];
#pragma unroll
    for (int nb = 0; nb < 4; ++nb)
#pragma unroll
        for (int e = 0; e < 16; ++e) accO[nb][e] = 0.f;

    float m_r = -1e30f, l_r = 0.f;
    const int ntiles = 2 * qb + 2;

    auto stage = [&](int buf, int tix) {
        const int j0s = tix * 64;
#pragma unroll
        for (int it = 0; it < 4; ++it) {
            int f = it * 256 + tid;
            int rk = f >> 4, ck = f & 15;
            gld16(kp + ((long)(j0s + rk) * Dd + ((ck ^ (rk & 7)) << 3)),
                  (char*)lds + buf * 16384 + f * 16);
            int rv = f >> 3, cv = f & 7;
            gld16(vp + ((long)rv * Tt + j0s + ((cv ^ (rv & 7)) << 3)),
                  (char*)lds + 32768 + buf * 16384 + f * 16);
        }
    };

    stage(0, 0);

    for (int tix = 0; tix < ntiles; ++tix) {
        const int cur = tix & 1;
        const int j0 = tix * 64;
        if (tix + 1 < ntiles) {
            stage(cur ^ 1, tix + 1);
            asm volatile("s_waitcnt vmcnt(8)" ::: "memory");
        } else {
            asm volatile("s_waitcnt vmcnt(0)" ::: "memory");
        }
        __builtin_amdgcn_s_barrier();

        const char* Kb = (const char*)lds + cur * 16384;
        const char* Vb = (const char*)lds + 32768 + cur * 16384;

        f32x16 sacc[2];
#pragma unroll
        for (int mb = 0; mb < 2; ++mb)
#pragma unroll
            for (int e = 0; e < 16; ++e) sacc[mb][e] = 0.f;

        __builtin_amdgcn_s_setprio(1);
#pragma unroll
        for (int mb = 0; mb < 2; ++mb) {
            int row = mb * 32 + iln;
            const char* Kr = Kb + row * 256;
            int sw = row & 7;
#pragma unroll
            for (int kk = 0; kk < 8; ++kk) {
                bf16x8 kf = *(const bf16x8*)(Kr + 16 * ((kk * 2 + h) ^ sw));
                sacc[mb] = __builtin_amdgcn_mfma_f32_32x32x16_bf16(kf, qf[kk], sacc[mb], 0, 0, 0);
            }
        }
        __builtin_amdgcn_s_setprio(0);

        const bool domask = (j0 + 63 > qb * 128);
        if (domask) {
#pragma unroll
            for (int mb = 0; mb < 2; ++mb)
#pragma unroll
                for (int reg = 0; reg < 16; ++reg) {
                    int j = j0 + mb * 32 + (reg & 3) + 8 * (reg >> 2) + 4 * h;
                    if (j > i_g) sacc[mb][reg] = -1e30f;
                }
        }

        float red[16];
#pragma unroll
        for (int r = 0; r < 16; ++r) red[r] = fmaxf(sacc[0][r], sacc[1][r]);
#pragma unroll
        for (int s = 8; s >= 1; s >>= 1)
#pragma unroll
            for (int r = 0; r < s; ++r) red[r] = fmaxf(red[r], red[r + s]);
        float mx = fmaxf(red[0], __shfl_xor(red[0], 32, 64));

        if (__any(mx > m_r + 8.f)) {
            float mn = fmaxf(m_r, mx);
            float corr = fexp2(m_r - mn);
            m_r = mn;
            l_r *= corr;
#pragma unroll
            for (int reg = 0; reg < 16; ++reg) {
                int rrow = (reg & 3) + 8 * (reg >> 2) + 4 * h;
                float c = __shfl(corr, rrow, 64);
#pragma unroll
                for (int nb = 0; nb < 4; ++nb) accO[nb][reg] *= c;
            }
        }

        float pe[2][16];
#pragma unroll
        for (int mb = 0; mb < 2; ++mb)
#pragma unroll
            for (int r = 0; r < 16; ++r) pe[mb][r] = fexp2(sacc[mb][r] - m_r);
        float sr[16];
#pragma unroll
        for (int r = 0; r < 16; ++r) sr[r] = pe[0][r] + pe[1][r];
#pragma unroll
        for (int s = 8; s >= 1; s >>= 1)
#pragma unroll
            for (int r = 0; r < s; ++r) sr[r] += sr[r + s];
        l_r += sr[0] + __shfl_xor(sr[0], 32, 64);

        unsigned int pu[2][8];
#pragma unroll
        for (int mb = 0; mb < 2; ++mb)
#pragma unroll
            for (int t = 0; t < 8; ++t)
                pu[mb][t] = cvt_pk_bf16(pe[mb][2 * t], pe[mb][2 * t + 1]);

        unsigned int rv2[2][4];
#pragma unroll
        for (int mb = 0; mb < 2; ++mb)
#pragma unroll
            for (int u = 0; u < 4; ++u) {
                unsigned int sv = h ? pu[mb][(u & 1) + 4 * (u >> 1)]
                                    : pu[mb][2 + (u & 1) + 4 * (u >> 1)];
                rv2[mb][u] = __shfl_xor(sv, 32, 64);
            }

        __builtin_amdgcn_s_setprio(1);
#pragma unroll
        for (int kk2 = 0; kk2 < 4; ++kk2) {
            const int mb = kk2 >> 1, c2 = kk2 & 1;
            unsigned int w0 = h ? rv2[mb][2 * c2 + 0] : pu[mb][4 * c2 + 0];
            unsigned int w1 = h ? rv2[mb][2 * c2 + 1] : pu[mb][4 * c2 + 1];
            unsigned int w2 = h ? pu[mb][4 * c2 + 2] : rv2[mb][2 * c2 + 0];
            unsigned int w3 = h ? pu[mb][4 * c2 + 3] : rv2[mb][2 * c2 + 1];
            uint4 aw; aw.x = w0; aw.y = w1; aw.z = w2; aw.w = w3;
            bf16x8 af = __builtin_bit_cast(bf16x8, aw);
#pragma unroll
            for (int nb = 0; nb < 4; ++nb) {
                int dd = nb * 32 + iln;
                int byte = dd * 128 + 16 * ((kk2 * 2 + h) ^ (dd & 7));
                bf16x8 vf = *(const bf16x8*)(Vb + byte);
                accO[nb] = __builtin_amdgcn_mfma_f32_32x32x16_bf16(af, vf, accO[nb], 0, 0, 0);
            }
        }
        __builtin_amdgcn_s_setprio(0);

        asm volatile("" ::: "memory");
        __builtin_amdgcn_s_barrier();
    }

    const int b = bh >> 4, hh = bh & 15;
    float invl = 1.f / l_r;
#pragma unroll
    for (int reg = 0; reg < 16; ++reg) {
        int rrow = (reg & 3) + 8 * (reg >> 2) + 4 * h;
        float iv = __shfl(invl, rrow, 64);
        int t = qb * 128 + wave * 32 + rrow;
        long base = ((long)(b * Tt + t) * Hh + hh) * Dd;
#pragma unroll
        for (int nb = 0; nb < 4; ++nb)
            o[base + nb * 32 + iln] = f2bf(accO[nb][reg] * iv);
    }
}

// ---------------------------------------------------------------- output projection GEMM
__global__ __launch_bounds__(256) void out_gemm(
    const unsigned short* __restrict__ oIn,
    const unsigned short* __restrict__ woT,
    float* __restrict__ out) {
    __shared__ __align__(16) unsigned short smem[32768];
    const int bm = blockIdx.x, bn = blockIdx.y;
    const int tid = threadIdx.x;
    const int lane = tid & 63;
    const int wave = tid >> 6;
    const int g = lane >> 4;
    const int ln = lane & 15;

    const unsigned short* arow = oIn + (long)bm * 128 * Mm;
    const unsigned short* brow = woT + (long)bn * 128 * Mm;

    f32x4 acc[2][8];
#pragma unroll
    for (int a = 0; a < 2; ++a)
#pragma unroll
        for (int b2 = 0; b2 < 8; ++b2)
#pragma unroll
            for (int e = 0; e < 4; ++e) acc[a][b2][e] = 0.f;

    auto stage = [&](int buf, int kt) {
        const int k0 = kt * 64;
#pragma unroll
        for (int it = 0; it < 4; ++it) {
            int f = it * 256 + tid;
            int r = f >> 3, c = f & 7;
            long off = (long)r * Mm + k0 + ((c ^ (r & 7)) << 3);
            gld16(arow + off, (char*)smem + buf * 32768 + f * 16);
            gld16(brow + off, (char*)smem + buf * 32768 + 16384 + f * 16);
        }
    };

    stage(0, 0);

    for (int kt = 0; kt < Mm / 64; ++kt) {
        const int cur = kt & 1;
        if (kt + 1 < Mm / 64) {
            stage(cur ^ 1, kt + 1);
            asm volatile("s_waitcnt vmcnt(8)" ::: "memory");
        } else {
            asm volatile("s_waitcnt vmcnt(0)" ::: "memory");
        }
        __builtin_amdgcn_s_barrier();

        const char* Ab = (const char*)smem + cur * 32768;
        const char* Bv = Ab + 16384;
#pragma unroll
        for (int kc = 0; kc < 2; ++kc) {
            bf16x8 af[2];
#pragma unroll
            for (int rf = 0; rf < 2; ++rf) {
                int row = wave * 32 + rf * 16 + ln;
                int byte = (row * 128 + kc * 64 + g * 16) ^ ((row & 7) << 4);
                af[rf] = *(const bf16x8*)(Ab + byte);
            }
#pragma unroll
            for (int ni = 0; ni < 8; ++ni) {
                int row = ni * 16 + ln;
                int byte = (row * 128 + kc * 64 + g * 16) ^ ((row & 7) << 4);
                bf16x8 bfv = *(const bf16x8*)(Bv + byte);
#pragma unroll
                for (int rf = 0; rf < 2; ++rf)
                    acc[rf][ni] = __builtin_amdgcn_mfma_f32_16x16x32_bf16(af[rf], bfv, acc[rf][ni], 0, 0, 0);
            }
        }
        asm volatile("" ::: "memory");
        __builtin_amdgcn_s_barrier();
    }

#pragma unroll
    for (int rf = 0; rf < 2; ++rf)
#pragma unroll
        for (int reg = 0; reg < 4; ++reg) {
            long row = bm * 128 + wave * 32 + rf * 16 + g * 4 + reg;
#pragma unroll
            for (int ni = 0; ni < 8; ++ni)
                out[row * Mm + bn * 128 + ni * 16 + ln] = acc[rf][ni][reg];
        }
}

// ---------------------------------------------------------------- launch

extern "C" void kernel_launch(void* const* d_in, const int* in_sizes, int n_in,
                              void* d_out, int out_size, void* d_ws, size_t ws_size,
                              hipStream_t stream) {
    const float* x    = (const float*)d_in[0];
    const float* w_aq = (const float*)d_in[1];
    const float* w_ak = (const float*)d_in[2];
    const float* w_av = (const float*)d_in[3];
    const float* w_ao = (const float*)d_in[4];
    float* out = (float*)d_out;

    char* ws = (char*)d_ws;
    const long SZ_BTM = 16777216;   // B*T*M * 2B
    const long SZ_W   = 8388608;    // 2048*2048 * 2B
    unsigned short* xb2 = (unsigned short*)(ws);
    unsigned short* qB  = (unsigned short*)(ws + SZ_BTM);
    unsigned short* kB  = (unsigned short*)(ws + 2 * SZ_BTM);
    unsigned short* vtB = (unsigned short*)(ws + 3 * SZ_BTM);
    unsigned short* oB  = (unsigned short*)(ws + 4 * SZ_BTM);
    unsigned short* wT2 = (unsigned short*)(ws + 5 * SZ_BTM);             // 24MB tiled qkv
    unsigned short* woT = (unsigned short*)(ws + 5 * SZ_BTM + 3 * SZ_W);
    float* cosT = (float*)(ws + 5 * SZ_BTM + 4 * SZ_W);
    float* sinT = (float*)(ws + 5 * SZ_BTM + 4 * SZ_W + 524288);

    cvt_x2<<<1024, 256, 0, stream>>>(x, xb2);
    w_qkv_tile<<<dim3(32, 48), 256, 0, stream>>>(w_aq, w_ak, w_av, wT2);
    transpose_cvt<<<dim3(64, 64, 1), 256, 0, stream>>>(w_ao, woT, 2048, 2048, 0, 0);
    rope_tab<<<512, 256, 0, stream>>>(cosT, sinT);

    proj_gemm6<<<dim3(768), 256, 0, stream>>>(xb2, wT2, qB, kB, vtB, cosT, sinT);
    attn_kernel<<<dim3(512), 256, 0, stream>>>(qB, kB, vtB, oB);
    out_gemm<<<dim3(32, 16), 256, 0, stream>>>(oB, woT, out);
}